// Round 9
// baseline (946.464 us; speedup 1.0000x reference)
//
#include <hip/hip_runtime.h>
#include <math.h>

#define EMB 32
#define HID 16
#define BY 4
#define NSYMP 15
#define NOPT 3
#define XCOLS (BY + 1 + NSYMP)   // 20

#define BSHIFT 8                 // 256 nodes per tgt bucket
#define BSZ 256
#define EPB 8192                 // edges per hist/scatter block
#define NCH 4                    // src chunks (65536 nodes = 4 MiB of f32 feature rows)
#define CSHIFT 16
#define NBINS_CAP 3328           // >= nbuck*NCH = 782*4 = 3128 ; 256*13
#define SPT 13                   // scan items per thread in scat (3328/256)

#define SCAN_T 256
#define SCAN_E 32
#define SCAN_B (SCAN_T * SCAN_E)  // 8192 elements per scan block

// ---- level-1: per-block composite-bin histogram (LDS atomics only) ----
__global__ __launch_bounds__(256) void k_hist(const int* __restrict__ tgt,
                                              const int* __restrict__ src,
                                              unsigned int* __restrict__ H,
                                              int nE, int gb1, int nbins) {
    __shared__ unsigned int h[NBINS_CAP];
    int b = blockIdx.x, tid = threadIdx.x;
    for (int k = tid; k < nbins; k += 256) h[k] = 0;
    __syncthreads();
    int e0 = b * EPB;
    int ecnt = min(EPB, nE - e0);
    for (int k = tid; k < ecnt; k += 256) {
        int t = tgt[e0 + k], s = src[e0 + k];
        atomicAdd(&h[((unsigned)t >> BSHIFT) * NCH + ((unsigned)s >> CSHIFT)], 1u);
    }
    __syncthreads();
    for (int q = tid; q < nbins; q += 256) H[(size_t)q * gb1 + b] = h[q];
}

// ---- scan step 1: per-block sums ----
__global__ __launch_bounds__(256) void k_bsum(const unsigned int* __restrict__ A,
                                              unsigned int* __restrict__ bsum, int m) {
    __shared__ unsigned int s[SCAN_T];
    int base = blockIdx.x * SCAN_B + threadIdx.x * SCAN_E;
    unsigned int t = 0;
#pragma unroll
    for (int k = 0; k < SCAN_E; ++k) { int idx = base + k; if (idx < m) t += A[idx]; }
    s[threadIdx.x] = t; __syncthreads();
    for (int off = SCAN_T / 2; off > 0; off >>= 1) {
        if (threadIdx.x < off) s[threadIdx.x] += s[threadIdx.x + off];
        __syncthreads();
    }
    if (threadIdx.x == 0) bsum[blockIdx.x] = s[0];
}

// ---- scan step 2: exclusive scan of block sums (single block, nb <= 512) ----
__global__ __launch_bounds__(512) void k_bscan(const unsigned int* __restrict__ bsum,
                                               unsigned int* __restrict__ boff, int nb) {
    __shared__ unsigned int s[512];
    unsigned int v = (threadIdx.x < (unsigned)nb) ? bsum[threadIdx.x] : 0u;
    s[threadIdx.x] = v; __syncthreads();
    for (int off = 1; off < 512; off <<= 1) {
        unsigned int t = (threadIdx.x >= (unsigned)off) ? s[threadIdx.x - off] : 0u;
        __syncthreads();
        s[threadIdx.x] += t;
        __syncthreads();
    }
    if (threadIdx.x < (unsigned)nb) boff[threadIdx.x] = s[threadIdx.x] - v;
}

// ---- scan step 3: per-element exclusive prefix (+ sentinel S[m]=total) ----
__global__ __launch_bounds__(256) void k_scan2(const unsigned int* __restrict__ A,
                                               const unsigned int* __restrict__ boff,
                                               unsigned int* __restrict__ S, int m, int total) {
    __shared__ unsigned int s[SCAN_T];
    int tid = threadIdx.x;
    int base = blockIdx.x * SCAN_B + tid * SCAN_E;
    unsigned int t = 0;
#pragma unroll
    for (int k = 0; k < SCAN_E; ++k) { int idx = base + k; if (idx < m) t += A[idx]; }
    s[tid] = t; __syncthreads();
    unsigned int own = t;
    for (int off = 1; off < SCAN_T; off <<= 1) {
        unsigned int u = (tid >= off) ? s[tid - off] : 0u;
        __syncthreads();
        s[tid] += u;
        __syncthreads();
    }
    unsigned int run = boff[blockIdx.x] + s[tid] - own;
#pragma unroll
    for (int k = 0; k < SCAN_E; ++k) {
        int idx = base + k;
        if (idx < m) { S[idx] = run; run += A[idx]; }
    }
    if (blockIdx.x == 0 && tid == 0) S[m] = (unsigned int)total;
}

// ---- level-1 scatter, LDS-staged: edges -> (tbucket,chunk)-grouped packed array ----
__global__ __launch_bounds__(256) void k_scat(const int* __restrict__ tgt,
                                              const int* __restrict__ src,
                                              const unsigned int* __restrict__ S,
                                              int* __restrict__ bp,
                                              int nE, int gb1, int nbins) {
    __shared__ int bpv[EPB];                 // 32 KB staged payload
    __shared__ unsigned short qid[EPB];      // 16 KB bin id per slot
    __shared__ unsigned int cur[NBINS_CAP];  // 13.3 KB
    __shared__ unsigned int dif[NBINS_CAP];  // 13.3 KB
    __shared__ unsigned int ps[256];
    int b = blockIdx.x, tid = threadIdx.x;
    for (int k = tid; k < NBINS_CAP; k += 256) cur[k] = 0;
    __syncthreads();
    int e0 = b * EPB;
    int ecnt = min(EPB, nE - e0);

    // pass 1: local histogram
    for (int k = tid; k < ecnt; k += 256) {
        int t = tgt[e0 + k], s = src[e0 + k];
        atomicAdd(&cur[((unsigned)t >> BSHIFT) * NCH + ((unsigned)s >> CSHIFT)], 1u);
    }
    __syncthreads();

    // exclusive scan over NBINS_CAP bins, SPT per thread
    unsigned int lv[SPT]; unsigned int tsum = 0;
#pragma unroll
    for (int k = 0; k < SPT; ++k) {
        int f = SPT * tid + k;
        unsigned int d = (f < NBINS_CAP) ? cur[f] : 0u;
        lv[k] = tsum; tsum += d;
    }
    ps[tid] = tsum; __syncthreads();
    for (int off = 1; off < 256; off <<= 1) {
        unsigned int u = (tid >= off) ? ps[tid - off] : 0u;
        __syncthreads();
        ps[tid] += u;
        __syncthreads();
    }
    unsigned int excl = ps[tid] - tsum;
    __syncthreads();   // everyone done reading cur as histogram
#pragma unroll
    for (int k = 0; k < SPT; ++k) {
        int f = SPT * tid + k;
        if (f < NBINS_CAP) { cur[f] = excl + lv[k]; dif[f] = excl + lv[k]; }
    }
    __syncthreads();
    for (int q = tid; q < nbins; q += 256)
        dif[q] = S[(size_t)q * gb1 + b] - dif[q];
    __syncthreads();

    // pass 2: scatter edges into LDS, grouped by bin
    for (int k = tid; k < ecnt; k += 256) {
        int t = tgt[e0 + k], s = src[e0 + k];
        int q = ((unsigned)t >> BSHIFT) * NCH + ((unsigned)s >> CSHIFT);
        unsigned int lpos = atomicAdd(&cur[q], 1u);
        bpv[lpos] = (s << BSHIFT) | (t & (BSZ - 1));
        qid[lpos] = (unsigned short)q;
    }
    __syncthreads();

    // pass 3: linear flush -> contiguous global writes per bin
    for (int k = tid; k < ecnt; k += 256) {
        int q = qid[k];
        bp[dif[q] + k] = bpv[k];
    }
}

// ---- per-bucket degree histogram -> dinv ----
__global__ __launch_bounds__(256) void k_bdeg(const unsigned int* __restrict__ S,
                                              const int* __restrict__ bp,
                                              float* __restrict__ dinv,
                                              int n, int gb1) {
    __shared__ unsigned int h[BSZ];
    int q = blockIdx.x, tid = threadIdx.x;
    h[tid] = 0; __syncthreads();
    unsigned int e0 = S[(size_t)q * NCH * gb1];
    unsigned int e1 = S[(size_t)(q + 1) * NCH * gb1];
    for (unsigned int e = e0 + tid; e < e1; e += 256)
        atomicAdd(&h[bp[e] & (BSZ - 1)], 1u);
    __syncthreads();
    int i = (q << BSHIFT) + tid;
    if (i < n) {
        float d = (float)(h[tid] + 1u);
        float r = rsqrtf(d);
        r = r * (1.5f - 0.5f * d * r * r);
        dinv[i] = r;
    }
}

// ---- embeddings + h@W1, pre-scaled by dinv ----
__global__ __launch_bounds__(256) void k_embed(const int* __restrict__ x,
                                               const float* __restrict__ birth_t,
                                               const float* __restrict__ gender_t,
                                               const float* __restrict__ symp_t,
                                               const float* __restrict__ W1,
                                               const float* __restrict__ dinv,
                                               float* __restrict__ hs1, int n) {
    __shared__ float sB[BY * EMB];
    __shared__ float sG[2 * EMB];
    __shared__ float sS[NSYMP * NOPT * EMB];
    __shared__ float sW[EMB * HID];
    for (int k = threadIdx.x; k < BY * EMB; k += blockDim.x) sB[k] = birth_t[k];
    for (int k = threadIdx.x; k < 2 * EMB; k += blockDim.x) sG[k] = gender_t[k];
    for (int k = threadIdx.x; k < NSYMP * NOPT * EMB; k += blockDim.x) sS[k] = symp_t[k];
    for (int k = threadIdx.x; k < EMB * HID; k += blockDim.x) sW[k] = W1[k];
    __syncthreads();

    int i = blockIdx.x * blockDim.x + threadIdx.x;
    if (i >= n) return;

    const int* xr = x + (size_t)i * XCOLS;
    int xv[XCOLS];
#pragma unroll
    for (int k = 0; k < XCOLS; ++k) xv[k] = xr[k];

    int bi = 0;
#pragma unroll
    for (int k = 1; k < BY; ++k) if (xv[k] > xv[bi]) bi = k;
    int gi = xv[BY];

    float ssum[EMB];
#pragma unroll
    for (int k = 0; k < EMB; ++k) ssum[k] = 0.f;
#pragma unroll
    for (int j = 0; j < NSYMP; ++j) {
        const float* row = &sS[(j * NOPT + xv[BY + 1 + j]) * EMB];
#pragma unroll
        for (int k = 0; k < EMB; ++k) ssum[k] += row[k];
    }

    float h[EMB];
#pragma unroll
    for (int k = 0; k < EMB; ++k)
        h[k] = (sB[bi * EMB + k] + sG[gi * EMB + k] + ssum[k] * (1.f / 15.f)) * (1.f / 3.f);

    float hp[HID];
#pragma unroll
    for (int j = 0; j < HID; ++j) hp[j] = 0.f;
#pragma unroll
    for (int k = 0; k < EMB; ++k) {
        float hv = h[k];
#pragma unroll
        for (int j = 0; j < HID; ++j) hp[j] += hv * sW[k * HID + j];
    }

    float dv = dinv[i];
    float4* o = (float4*)(hs1 + (size_t)i * HID);
#pragma unroll
    for (int q = 0; q < 4; ++q) {
        float4 v;
        v.x = dv * hp[q * 4 + 0];
        v.y = dv * hp[q * 4 + 1];
        v.z = dv * hp[q * 4 + 2];
        v.w = dv * hp[q * 4 + 3];
        o[q] = v;
    }
}

// ---- layer 1 push: per-bucket LDS accumulation + fused ELU/W2/Wl epilogue ----
// One block per 256-node bucket; all 782 blocks co-resident -> chunk phases align.
__global__ __launch_bounds__(256) void k_push1(const unsigned int* __restrict__ S,
                                               const int* __restrict__ bp,
                                               const float* __restrict__ A,
                                               const float* __restrict__ dinv,
                                               const float* __restrict__ W2,
                                               const float* __restrict__ b1,
                                               const float* __restrict__ Wl,
                                               float* __restrict__ z, int n, int gb1) {
    __shared__ float acc[BSZ * HID];   // 16 KB
    __shared__ float sW[HID * HID];
    __shared__ float sb[HID];
    __shared__ float sw[HID];
    int q = blockIdx.x, tid = threadIdx.x;
    if (tid < HID * HID) sW[tid] = W2[tid];
    if (tid < HID) { sb[tid] = b1[tid]; sw[tid] = Wl[tid]; }
    for (int k = tid; k < BSZ * HID; k += 256) acc[k] = 0.f;
    __syncthreads();

    unsigned int e0 = S[(size_t)q * NCH * gb1];
    unsigned int e1 = S[(size_t)(q + 1) * NCH * gb1];

    int quart = tid >> 2, c = tid & 3;       // 64 quartets; quartet handles 1 edge/step
    unsigned int e = e0 + quart;
    for (; e + 64 < e1; e += 128) {
        int v1 = bp[e], v2 = bp[e + 64];
        int s1 = v1 >> BSHIFT, t1 = v1 & (BSZ - 1);
        int s2 = v2 >> BSHIFT, t2 = v2 & (BSZ - 1);
        float4 va = *(const float4*)(A + (size_t)s1 * HID + c * 4);
        float4 vb = *(const float4*)(A + (size_t)s2 * HID + c * 4);
        float* p1 = &acc[t1 * HID + c * 4];
        unsafeAtomicAdd(p1 + 0, va.x); unsafeAtomicAdd(p1 + 1, va.y);
        unsafeAtomicAdd(p1 + 2, va.z); unsafeAtomicAdd(p1 + 3, va.w);
        float* p2 = &acc[t2 * HID + c * 4];
        unsafeAtomicAdd(p2 + 0, vb.x); unsafeAtomicAdd(p2 + 1, vb.y);
        unsafeAtomicAdd(p2 + 2, vb.z); unsafeAtomicAdd(p2 + 3, vb.w);
    }
    if (e < e1) {
        int v1 = bp[e];
        int s1 = v1 >> BSHIFT, t1 = v1 & (BSZ - 1);
        float4 va = *(const float4*)(A + (size_t)s1 * HID + c * 4);
        float* p1 = &acc[t1 * HID + c * 4];
        unsafeAtomicAdd(p1 + 0, va.x); unsafeAtomicAdd(p1 + 1, va.y);
        unsafeAtomicAdd(p1 + 2, va.z); unsafeAtomicAdd(p1 + 3, va.w);
    }
    __syncthreads();

    // epilogue: 16 groups x 16 lanes; group g handles nodes g, 16+g, ...
    int g = tid >> 4, l = tid & 15;
    int lanebase = (tid & 63) & ~15;
    int base = q << BSHIFT;
    for (int rr = 0; rr < BSZ / 16; ++rr) {
        int loc = rr * 16 + g;
        int i = base + loc;
        if (i < n) {
            float dv = dinv[i];
            float v = dv * (acc[loc * HID + l] + A[(size_t)i * HID + l]) + sb[l];
            float h1 = (v > 0.f) ? v : expm1f(v);
            float hp = 0.f;
#pragma unroll
            for (int k = 0; k < HID; ++k)
                hp += __shfl(h1, lanebase + k, 64) * sW[k * HID + l];
            float p = dv * hp * sw[l];
#pragma unroll
            for (int off = 8; off > 0; off >>= 1) p += __shfl_xor(p, off, 64);
            if (l == 0) z[i] = p;
        }
    }
}

// ---- layer 2 push: scalar z accumulation per bucket + final affine ----
__global__ __launch_bounds__(256) void k_push2(const unsigned int* __restrict__ S,
                                               const int* __restrict__ bp,
                                               const float* __restrict__ z,
                                               const float* __restrict__ dinv,
                                               const float* __restrict__ b2,
                                               const float* __restrict__ Wl,
                                               const float* __restrict__ bl,
                                               float* __restrict__ out, int n, int gb1) {
    __shared__ float acc[BSZ];
    __shared__ float sc0;
    int q = blockIdx.x, tid = threadIdx.x;
    if (tid == 0) {
        float c = 0.f;
#pragma unroll
        for (int k = 0; k < HID; ++k) c += b2[k] * Wl[k];
        sc0 = c + bl[0];
    }
    acc[tid] = 0.f;
    __syncthreads();

    unsigned int e0 = S[(size_t)q * NCH * gb1];
    unsigned int e1 = S[(size_t)(q + 1) * NCH * gb1];
    unsigned int e = e0 + tid;
    for (; e + 256 < e1; e += 512) {
        int v1 = bp[e], v2 = bp[e + 256];
        float z1 = z[v1 >> BSHIFT], z2 = z[v2 >> BSHIFT];
        unsafeAtomicAdd(&acc[v1 & (BSZ - 1)], z1);
        unsafeAtomicAdd(&acc[v2 & (BSZ - 1)], z2);
    }
    if (e < e1) {
        int v1 = bp[e];
        unsafeAtomicAdd(&acc[v1 & (BSZ - 1)], z[v1 >> BSHIFT]);
    }
    __syncthreads();

    int i = (q << BSHIFT) + tid;
    if (i < n) out[i] = dinv[i] * (acc[tid] + z[i]) + sc0;
}

extern "C" void kernel_launch(void* const* d_in, const int* in_sizes, int n_in,
                              void* d_out, int out_size, void* d_ws, size_t ws_size,
                              hipStream_t stream) {
    const int*   x        = (const int*)d_in[0];
    const int*   ei       = (const int*)d_in[1];   // int32 per harness conversion
    const float* birth_t  = (const float*)d_in[2];
    const float* gender_t = (const float*)d_in[3];
    const float* symp_t   = (const float*)d_in[4];
    const float* W1       = (const float*)d_in[5];
    const float* b1       = (const float*)d_in[6];
    const float* W2       = (const float*)d_in[7];
    const float* b2       = (const float*)d_in[8];
    const float* Wl       = (const float*)d_in[9];
    const float* bl       = (const float*)d_in[10];
    float*       out      = (float*)d_out;

    const int n  = in_sizes[0] / XCOLS;
    const int nE = in_sizes[1] / 2;
    const int* src = ei;
    const int* tgt = ei + nE;

    const int nbuck = (n + BSZ - 1) >> BSHIFT;            // 782
    const int nbins = nbuck * NCH;                        // 3128 (<= NBINS_CAP)
    const int gb1   = (nE + EPB - 1) / EPB;               // 782
    const int M     = nbins * gb1;                        // ~2.45M
    const int nb    = (M + SCAN_B - 1) / SCAN_B;          // ~299 (<=512)

    // workspace layout (256B aligned slices)
    char* ws = (char*)d_ws;
    size_t off = 0;
    auto alloc = [&](size_t bytes) { char* p = ws + off; off = (off + bytes + 255) & ~(size_t)255; return p; };
    unsigned int* H    = (unsigned int*)alloc((size_t)M * 4);
    unsigned int* S    = (unsigned int*)alloc(((size_t)M + 1) * 4);
    unsigned int* bsum = (unsigned int*)alloc(512 * 4);
    unsigned int* boff = (unsigned int*)alloc(512 * 4);
    int*          bp   = (int*)alloc((size_t)nE * 4);
    float*        dinv = (float*)alloc((size_t)n * 4);
    float*        A    = (float*)alloc((size_t)n * HID * 4);
    float*        z    = (float*)alloc((size_t)n * 4);

    const int BLK = 256;
    const int gN = (n + BLK - 1) / BLK;

    k_hist <<<gb1, BLK, 0, stream>>>(tgt, src, H, nE, gb1, nbins);
    k_bsum <<<nb, SCAN_T, 0, stream>>>(H, bsum, M);
    k_bscan<<<1, 512, 0, stream>>>(bsum, boff, nb);
    k_scan2<<<nb, SCAN_T, 0, stream>>>(H, boff, S, M, nE);
    k_scat <<<gb1, BLK, 0, stream>>>(tgt, src, S, bp, nE, gb1, nbins);
    k_bdeg <<<nbuck, BLK, 0, stream>>>(S, bp, dinv, n, gb1);
    k_embed<<<gN, BLK, 0, stream>>>(x, birth_t, gender_t, symp_t, W1, dinv, A, n);
    k_push1<<<nbuck, BLK, 0, stream>>>(S, bp, A, dinv, W2, b1, Wl, z, n, gb1);
    k_push2<<<nbuck, BLK, 0, stream>>>(S, bp, z, dinv, b2, Wl, bl, out, n, gb1);
}

// Round 10
// 378.558 us; speedup vs baseline: 2.5002x; 2.5002x over previous
//
#include <hip/hip_runtime.h>
#include <math.h>

#define EMB 32
#define HID 16
#define BY 4
#define NSYMP 15
#define NOPT 3
#define XCOLS (BY + 1 + NSYMP)   // 20

#define BSHIFT 8                 // 256 nodes per tgt bucket
#define BSZ 256
#define EPB 8192                 // edges per hist/scatter block
#define NCH 4                    // src chunks (65536 nodes = 4 MiB of f32 feature rows)
#define CSHIFT 16
#define NBINS_CAP 3328           // >= nbuck*NCH = 782*4 = 3128 ; 256*13
#define SPT 13                   // scan items per thread in scat (3328/256)
#define LCAP 4096                // staged edges per (bucket,chunk) bin (mean ~2048)

#define SCAN_T 256
#define SCAN_E 32
#define SCAN_B (SCAN_T * SCAN_E)  // 8192 elements per scan block

// ---- level-1: per-block composite-bin histogram (LDS atomics only) ----
__global__ __launch_bounds__(256) void k_hist(const int* __restrict__ tgt,
                                              const int* __restrict__ src,
                                              unsigned int* __restrict__ H,
                                              int nE, int gb1, int nbins) {
    __shared__ unsigned int h[NBINS_CAP];
    int b = blockIdx.x, tid = threadIdx.x;
    for (int k = tid; k < nbins; k += 256) h[k] = 0;
    __syncthreads();
    int e0 = b * EPB;
    int ecnt = min(EPB, nE - e0);
    for (int k = tid; k < ecnt; k += 256) {
        int t = tgt[e0 + k], s = src[e0 + k];
        atomicAdd(&h[((unsigned)t >> BSHIFT) * NCH + ((unsigned)s >> CSHIFT)], 1u);
    }
    __syncthreads();
    for (int q = tid; q < nbins; q += 256) H[(size_t)q * gb1 + b] = h[q];
}

// ---- scan step 1: per-block sums ----
__global__ __launch_bounds__(256) void k_bsum(const unsigned int* __restrict__ A,
                                              unsigned int* __restrict__ bsum, int m) {
    __shared__ unsigned int s[SCAN_T];
    int base = blockIdx.x * SCAN_B + threadIdx.x * SCAN_E;
    unsigned int t = 0;
#pragma unroll
    for (int k = 0; k < SCAN_E; ++k) { int idx = base + k; if (idx < m) t += A[idx]; }
    s[threadIdx.x] = t; __syncthreads();
    for (int off = SCAN_T / 2; off > 0; off >>= 1) {
        if (threadIdx.x < off) s[threadIdx.x] += s[threadIdx.x + off];
        __syncthreads();
    }
    if (threadIdx.x == 0) bsum[blockIdx.x] = s[0];
}

// ---- scan step 2: exclusive scan of block sums (single block, nb <= 512) ----
__global__ __launch_bounds__(512) void k_bscan(const unsigned int* __restrict__ bsum,
                                               unsigned int* __restrict__ boff, int nb) {
    __shared__ unsigned int s[512];
    unsigned int v = (threadIdx.x < (unsigned)nb) ? bsum[threadIdx.x] : 0u;
    s[threadIdx.x] = v; __syncthreads();
    for (int off = 1; off < 512; off <<= 1) {
        unsigned int t = (threadIdx.x >= (unsigned)off) ? s[threadIdx.x - off] : 0u;
        __syncthreads();
        s[threadIdx.x] += t;
        __syncthreads();
    }
    if (threadIdx.x < (unsigned)nb) boff[threadIdx.x] = s[threadIdx.x] - v;
}

// ---- scan step 3: per-element exclusive prefix (+ sentinel S[m]=total) ----
__global__ __launch_bounds__(256) void k_scan2(const unsigned int* __restrict__ A,
                                               const unsigned int* __restrict__ boff,
                                               unsigned int* __restrict__ S, int m, int total) {
    __shared__ unsigned int s[SCAN_T];
    int tid = threadIdx.x;
    int base = blockIdx.x * SCAN_B + tid * SCAN_E;
    unsigned int t = 0;
#pragma unroll
    for (int k = 0; k < SCAN_E; ++k) { int idx = base + k; if (idx < m) t += A[idx]; }
    s[tid] = t; __syncthreads();
    unsigned int own = t;
    for (int off = 1; off < SCAN_T; off <<= 1) {
        unsigned int u = (tid >= off) ? s[tid - off] : 0u;
        __syncthreads();
        s[tid] += u;
        __syncthreads();
    }
    unsigned int run = boff[blockIdx.x] + s[tid] - own;
#pragma unroll
    for (int k = 0; k < SCAN_E; ++k) {
        int idx = base + k;
        if (idx < m) { S[idx] = run; run += A[idx]; }
    }
    if (blockIdx.x == 0 && tid == 0) S[m] = (unsigned int)total;
}

// ---- level-1 scatter, LDS-staged: edges -> (tbucket,chunk)-grouped packed array ----
__global__ __launch_bounds__(256) void k_scat(const int* __restrict__ tgt,
                                              const int* __restrict__ src,
                                              const unsigned int* __restrict__ S,
                                              int* __restrict__ bp,
                                              int nE, int gb1, int nbins) {
    __shared__ int bpv[EPB];                 // 32 KB staged payload
    __shared__ unsigned short qid[EPB];      // 16 KB bin id per slot
    __shared__ unsigned int cur[NBINS_CAP];  // 13.3 KB
    __shared__ unsigned int dif[NBINS_CAP];  // 13.3 KB
    __shared__ unsigned int ps[256];
    int b = blockIdx.x, tid = threadIdx.x;
    for (int k = tid; k < NBINS_CAP; k += 256) cur[k] = 0;
    __syncthreads();
    int e0 = b * EPB;
    int ecnt = min(EPB, nE - e0);

    for (int k = tid; k < ecnt; k += 256) {
        int t = tgt[e0 + k], s = src[e0 + k];
        atomicAdd(&cur[((unsigned)t >> BSHIFT) * NCH + ((unsigned)s >> CSHIFT)], 1u);
    }
    __syncthreads();

    unsigned int lv[SPT]; unsigned int tsum = 0;
#pragma unroll
    for (int k = 0; k < SPT; ++k) {
        int f = SPT * tid + k;
        unsigned int d = (f < NBINS_CAP) ? cur[f] : 0u;
        lv[k] = tsum; tsum += d;
    }
    ps[tid] = tsum; __syncthreads();
    for (int off = 1; off < 256; off <<= 1) {
        unsigned int u = (tid >= off) ? ps[tid - off] : 0u;
        __syncthreads();
        ps[tid] += u;
        __syncthreads();
    }
    unsigned int excl = ps[tid] - tsum;
    __syncthreads();
#pragma unroll
    for (int k = 0; k < SPT; ++k) {
        int f = SPT * tid + k;
        if (f < NBINS_CAP) { cur[f] = excl + lv[k]; dif[f] = excl + lv[k]; }
    }
    __syncthreads();
    for (int q = tid; q < nbins; q += 256)
        dif[q] = S[(size_t)q * gb1 + b] - dif[q];
    __syncthreads();

    for (int k = tid; k < ecnt; k += 256) {
        int t = tgt[e0 + k], s = src[e0 + k];
        int q = ((unsigned)t >> BSHIFT) * NCH + ((unsigned)s >> CSHIFT);
        unsigned int lpos = atomicAdd(&cur[q], 1u);
        bpv[lpos] = (s << BSHIFT) | (t & (BSZ - 1));
        qid[lpos] = (unsigned short)q;
    }
    __syncthreads();

    for (int k = tid; k < ecnt; k += 256) {
        int q = qid[k];
        bp[dif[q] + k] = bpv[k];
    }
}

// ---- per-bucket degree histogram -> dinv ----
__global__ __launch_bounds__(256) void k_bdeg(const unsigned int* __restrict__ S,
                                              const int* __restrict__ bp,
                                              float* __restrict__ dinv,
                                              int n, int gb1) {
    __shared__ unsigned int h[BSZ];
    int q = blockIdx.x, tid = threadIdx.x;
    h[tid] = 0; __syncthreads();
    unsigned int e0 = S[(size_t)q * NCH * gb1];
    unsigned int e1 = S[(size_t)(q + 1) * NCH * gb1];
    for (unsigned int e = e0 + tid; e < e1; e += 256)
        atomicAdd(&h[bp[e] & (BSZ - 1)], 1u);
    __syncthreads();
    int i = (q << BSHIFT) + tid;
    if (i < n) {
        float d = (float)(h[tid] + 1u);
        float r = rsqrtf(d);
        r = r * (1.5f - 0.5f * d * r * r);
        dinv[i] = r;
    }
}

// ---- embeddings + h@W1, pre-scaled by dinv ----
__global__ __launch_bounds__(256) void k_embed(const int* __restrict__ x,
                                               const float* __restrict__ birth_t,
                                               const float* __restrict__ gender_t,
                                               const float* __restrict__ symp_t,
                                               const float* __restrict__ W1,
                                               const float* __restrict__ dinv,
                                               float* __restrict__ hs1, int n) {
    __shared__ float sB[BY * EMB];
    __shared__ float sG[2 * EMB];
    __shared__ float sS[NSYMP * NOPT * EMB];
    __shared__ float sW[EMB * HID];
    for (int k = threadIdx.x; k < BY * EMB; k += blockDim.x) sB[k] = birth_t[k];
    for (int k = threadIdx.x; k < 2 * EMB; k += blockDim.x) sG[k] = gender_t[k];
    for (int k = threadIdx.x; k < NSYMP * NOPT * EMB; k += blockDim.x) sS[k] = symp_t[k];
    for (int k = threadIdx.x; k < EMB * HID; k += blockDim.x) sW[k] = W1[k];
    __syncthreads();

    int i = blockIdx.x * blockDim.x + threadIdx.x;
    if (i >= n) return;

    const int* xr = x + (size_t)i * XCOLS;
    int xv[XCOLS];
#pragma unroll
    for (int k = 0; k < XCOLS; ++k) xv[k] = xr[k];

    int bi = 0;
#pragma unroll
    for (int k = 1; k < BY; ++k) if (xv[k] > xv[bi]) bi = k;
    int gi = xv[BY];

    float ssum[EMB];
#pragma unroll
    for (int k = 0; k < EMB; ++k) ssum[k] = 0.f;
#pragma unroll
    for (int j = 0; j < NSYMP; ++j) {
        const float* row = &sS[(j * NOPT + xv[BY + 1 + j]) * EMB];
#pragma unroll
        for (int k = 0; k < EMB; ++k) ssum[k] += row[k];
    }

    float h[EMB];
#pragma unroll
    for (int k = 0; k < EMB; ++k)
        h[k] = (sB[bi * EMB + k] + sG[gi * EMB + k] + ssum[k] * (1.f / 15.f)) * (1.f / 3.f);

    float hp[HID];
#pragma unroll
    for (int j = 0; j < HID; ++j) hp[j] = 0.f;
#pragma unroll
    for (int k = 0; k < EMB; ++k) {
        float hv = h[k];
#pragma unroll
        for (int j = 0; j < HID; ++j) hp[j] += hv * sW[k * HID + j];
    }

    float dv = dinv[i];
    float4* o = (float4*)(hs1 + (size_t)i * HID);
#pragma unroll
    for (int q = 0; q < 4; ++q) {
        float4 v;
        v.x = dv * hp[q * 4 + 0];
        v.y = dv * hp[q * 4 + 1];
        v.z = dv * hp[q * 4 + 2];
        v.w = dv * hp[q * 4 + 3];
        o[q] = v;
    }
}

// ---- layer 1: per-bucket in-LDS counting sort + quartet-float4 register pull.
// One block per 256-node bucket; all 782 blocks co-resident, walking chunks in
// lockstep (L2 phase alignment) with zero f32 atomics.
__global__ __launch_bounds__(256) void k_fuse1(const unsigned int* __restrict__ S,
                                               const int* __restrict__ bp,
                                               const float* __restrict__ A,
                                               const float* __restrict__ dinv,
                                               const float* __restrict__ W2,
                                               const float* __restrict__ b1,
                                               const float* __restrict__ Wl,
                                               float* __restrict__ z, int n, int gb1) {
    __shared__ float accL[BSZ * HID];        // 16 KB running acc per node
    __shared__ int lst[LCAP];                // 16 KB chunk-sorted src ids
    __shared__ unsigned int h[BSZ];          // per-node counts (this chunk)
    __shared__ unsigned int st[BSZ];         // per-node start (this chunk)
    __shared__ unsigned int cu[BSZ];         // scatter cursors
    __shared__ unsigned int ps[256];
    __shared__ float sW[HID * HID];
    __shared__ float sb[HID];
    __shared__ float sw[HID];
    int q = blockIdx.x, tid = threadIdx.x;
    if (tid < HID * HID) sW[tid] = W2[tid];
    if (tid < HID) { sb[tid] = b1[tid]; sw[tid] = Wl[tid]; }
    for (int k = tid; k < BSZ * HID; k += 256) accL[k] = 0.f;

    int g = tid >> 4, l = tid & 15;
    int qq = l >> 2, c4 = l & 3;

    for (int c = 0; c < NCH; ++c) {
        __syncthreads();                     // previous pull done
        h[tid] = 0;
        __syncthreads();
        unsigned int e0 = S[(size_t)(q * NCH + c) * gb1];
        unsigned int e1 = S[(size_t)(q * NCH + c + 1) * gb1];
        int cnt = (int)(e1 - e0);
        for (int k = tid; k < cnt; k += 256)
            atomicAdd(&h[bp[e0 + k] & (BSZ - 1)], 1u);
        __syncthreads();
        unsigned int own = h[tid];
        ps[tid] = own; __syncthreads();
        for (int off = 1; off < 256; off <<= 1) {
            unsigned int u = (tid >= off) ? ps[tid - off] : 0u;
            __syncthreads();
            ps[tid] += u;
            __syncthreads();
        }
        unsigned int excl = ps[tid] - own;
        st[tid] = excl; cu[tid] = excl;
        __syncthreads();
        for (int k = tid; k < cnt; k += 256) {
            int v = bp[e0 + k];
            unsigned int pos = atomicAdd(&cu[v & (BSZ - 1)], 1u);
            lst[pos] = (unsigned)v >> BSHIFT;
        }
        __syncthreads();

        // pull: group g handles nodes rr*16+g; quartet qq, row-chunk c4
        for (int rr = 0; rr < BSZ / 16; ++rr) {
            int loc = rr * 16 + g;
            unsigned int r0 = st[loc], r1 = r0 + h[loc];
            float ax = 0.f, ay = 0.f, az = 0.f, aw = 0.f;
            for (unsigned int e = r0 + qq; e < r1; e += 4) {
                int s = lst[e];
                float4 va = *(const float4*)(A + (size_t)s * HID + c4 * 4);
                ax += va.x; ay += va.y; az += va.z; aw += va.w;
            }
            ax += __shfl_xor(ax, 4, 64); ay += __shfl_xor(ay, 4, 64);
            az += __shfl_xor(az, 4, 64); aw += __shfl_xor(aw, 4, 64);
            ax += __shfl_xor(ax, 8, 64); ay += __shfl_xor(ay, 8, 64);
            az += __shfl_xor(az, 8, 64); aw += __shfl_xor(aw, 8, 64);
            if (qq == 0) {                   // lanes 0..3, c4 == l
                float4* pa = (float4*)&accL[loc * HID + c4 * 4];
                float4 o = *pa;
                o.x += ax; o.y += ay; o.z += az; o.w += aw;
                *pa = o;
            }
        }
    }
    __syncthreads();

    // epilogue: group g, lane l; node loc = rr*16+g
    int lanebase = (tid & 63) & ~15;
    int base = q << BSHIFT;
    for (int rr = 0; rr < BSZ / 16; ++rr) {
        int loc = rr * 16 + g;
        int i = base + loc;
        if (i < n) {
            float dv = dinv[i];
            float v = dv * (accL[loc * HID + l] + A[(size_t)i * HID + l]) + sb[l];
            float h1 = (v > 0.f) ? v : expm1f(v);
            float hp = 0.f;
#pragma unroll
            for (int k = 0; k < HID; ++k)
                hp += __shfl(h1, lanebase + k, 64) * sW[k * HID + l];
            float p = dv * hp * sw[l];
#pragma unroll
            for (int off = 8; off > 0; off >>= 1) p += __shfl_xor(p, off, 64);
            if (l == 0) z[i] = p;
        }
    }
}

// ---- layer 2: same in-LDS sort, scalar pull (lane per node, reg acc) ----
__global__ __launch_bounds__(256) void k_fuse2(const unsigned int* __restrict__ S,
                                               const int* __restrict__ bp,
                                               const float* __restrict__ z,
                                               const float* __restrict__ dinv,
                                               const float* __restrict__ b2,
                                               const float* __restrict__ Wl,
                                               const float* __restrict__ bl,
                                               float* __restrict__ out, int n, int gb1) {
    __shared__ int lst[LCAP];
    __shared__ unsigned int h[BSZ];
    __shared__ unsigned int st[BSZ];
    __shared__ unsigned int cu[BSZ];
    __shared__ unsigned int ps[256];
    __shared__ float sc0;
    int q = blockIdx.x, tid = threadIdx.x;
    if (tid == 0) {
        float c = 0.f;
#pragma unroll
        for (int k = 0; k < HID; ++k) c += b2[k] * Wl[k];
        sc0 = c + bl[0];
    }

    float accr = 0.f;
    for (int c = 0; c < NCH; ++c) {
        __syncthreads();
        h[tid] = 0;
        __syncthreads();
        unsigned int e0 = S[(size_t)(q * NCH + c) * gb1];
        unsigned int e1 = S[(size_t)(q * NCH + c + 1) * gb1];
        int cnt = (int)(e1 - e0);
        for (int k = tid; k < cnt; k += 256)
            atomicAdd(&h[bp[e0 + k] & (BSZ - 1)], 1u);
        __syncthreads();
        unsigned int own = h[tid];
        ps[tid] = own; __syncthreads();
        for (int off = 1; off < 256; off <<= 1) {
            unsigned int u = (tid >= off) ? ps[tid - off] : 0u;
            __syncthreads();
            ps[tid] += u;
            __syncthreads();
        }
        unsigned int excl = ps[tid] - own;
        st[tid] = excl; cu[tid] = excl;
        __syncthreads();
        for (int k = tid; k < cnt; k += 256) {
            int v = bp[e0 + k];
            unsigned int pos = atomicAdd(&cu[v & (BSZ - 1)], 1u);
            lst[pos] = (unsigned)v >> BSHIFT;
        }
        __syncthreads();
        unsigned int r0 = st[tid], r1 = r0 + h[tid];
        for (unsigned int e = r0; e < r1; ++e) accr += z[lst[e]];
    }
    __syncthreads();

    int i = (q << BSHIFT) + tid;
    if (i < n) out[i] = dinv[i] * (accr + z[i]) + sc0;
}

extern "C" void kernel_launch(void* const* d_in, const int* in_sizes, int n_in,
                              void* d_out, int out_size, void* d_ws, size_t ws_size,
                              hipStream_t stream) {
    const int*   x        = (const int*)d_in[0];
    const int*   ei       = (const int*)d_in[1];   // int32 per harness conversion
    const float* birth_t  = (const float*)d_in[2];
    const float* gender_t = (const float*)d_in[3];
    const float* symp_t   = (const float*)d_in[4];
    const float* W1       = (const float*)d_in[5];
    const float* b1       = (const float*)d_in[6];
    const float* W2       = (const float*)d_in[7];
    const float* b2       = (const float*)d_in[8];
    const float* Wl       = (const float*)d_in[9];
    const float* bl       = (const float*)d_in[10];
    float*       out      = (float*)d_out;

    const int n  = in_sizes[0] / XCOLS;
    const int nE = in_sizes[1] / 2;
    const int* src = ei;
    const int* tgt = ei + nE;

    const int nbuck = (n + BSZ - 1) >> BSHIFT;            // 782
    const int nbins = nbuck * NCH;                        // 3128 (<= NBINS_CAP)
    const int gb1   = (nE + EPB - 1) / EPB;               // 782
    const int M     = nbins * gb1;                        // ~2.45M
    const int nb    = (M + SCAN_B - 1) / SCAN_B;          // ~299 (<=512)

    // workspace layout (256B aligned slices)
    char* ws = (char*)d_ws;
    size_t off = 0;
    auto alloc = [&](size_t bytes) { char* p = ws + off; off = (off + bytes + 255) & ~(size_t)255; return p; };
    unsigned int* H    = (unsigned int*)alloc((size_t)M * 4);
    unsigned int* S    = (unsigned int*)alloc(((size_t)M + 1) * 4);
    unsigned int* bsum = (unsigned int*)alloc(512 * 4);
    unsigned int* boff = (unsigned int*)alloc(512 * 4);
    int*          bp   = (int*)alloc((size_t)nE * 4);
    float*        dinv = (float*)alloc((size_t)n * 4);
    float*        A    = (float*)alloc((size_t)n * HID * 4);
    float*        z    = (float*)alloc((size_t)n * 4);

    const int BLK = 256;
    const int gN = (n + BLK - 1) / BLK;

    k_hist <<<gb1, BLK, 0, stream>>>(tgt, src, H, nE, gb1, nbins);
    k_bsum <<<nb, SCAN_T, 0, stream>>>(H, bsum, M);
    k_bscan<<<1, 512, 0, stream>>>(bsum, boff, nb);
    k_scan2<<<nb, SCAN_T, 0, stream>>>(H, boff, S, M, nE);
    k_scat <<<gb1, BLK, 0, stream>>>(tgt, src, S, bp, nE, gb1, nbins);
    k_bdeg <<<nbuck, BLK, 0, stream>>>(S, bp, dinv, n, gb1);
    k_embed<<<gN, BLK, 0, stream>>>(x, birth_t, gender_t, symp_t, W1, dinv, A, n);
    k_fuse1<<<nbuck, BLK, 0, stream>>>(S, bp, A, dinv, W2, b1, Wl, z, n, gb1);
    k_fuse2<<<nbuck, BLK, 0, stream>>>(S, bp, z, dinv, b2, Wl, bl, out, n, gb1);
}

// Round 11
// 299.986 us; speedup vs baseline: 3.1550x; 1.2619x over previous
//
#include <hip/hip_runtime.h>
#include <math.h>

#define EMB 32
#define HID 16
#define BY 4
#define NSYMP 15
#define NOPT 3
#define XCOLS (BY + 1 + NSYMP)   // 20

#define BSHIFT 8                 // 256 nodes per tgt bucket
#define BSZ 256
#define EPB 8192                 // edges per hist/scatter block
#define NBCAP 1024               // padded bin capacity (>= nbuck=782)
#define SPT 4                    // scan items per thread in scat (1024/256)
#define LSTCAP 10240             // staged col entries per bucket (mean 8184, +22 sigma)

#define SCAN_T 256
#define SCAN_E 32
#define SCAN_B (SCAN_T * SCAN_E)  // 8192 elements per scan block

// ---- level-1: per-block bucket histogram (LDS atomics only) ----
__global__ __launch_bounds__(256) void k_hist(const int* __restrict__ tgt,
                                              unsigned int* __restrict__ H,
                                              int nE, int gb1, int nbins) {
    __shared__ unsigned int h[NBCAP];
    int b = blockIdx.x, tid = threadIdx.x;
    for (int k = tid; k < NBCAP; k += 256) h[k] = 0;
    __syncthreads();
    int e0 = b * EPB;
    int ecnt = min(EPB, nE - e0);
    for (int k = tid; k < ecnt; k += 256)
        atomicAdd(&h[(unsigned)tgt[e0 + k] >> BSHIFT], 1u);
    __syncthreads();
    for (int q = tid; q < nbins; q += 256) H[(size_t)q * gb1 + b] = h[q];
}

// ---- scan step 1: per-block sums ----
__global__ __launch_bounds__(256) void k_bsum(const unsigned int* __restrict__ A,
                                              unsigned int* __restrict__ bsum, int m) {
    __shared__ unsigned int s[SCAN_T];
    int base = blockIdx.x * SCAN_B + threadIdx.x * SCAN_E;
    unsigned int t = 0;
#pragma unroll
    for (int k = 0; k < SCAN_E; ++k) { int idx = base + k; if (idx < m) t += A[idx]; }
    s[threadIdx.x] = t; __syncthreads();
    for (int off = SCAN_T / 2; off > 0; off >>= 1) {
        if (threadIdx.x < off) s[threadIdx.x] += s[threadIdx.x + off];
        __syncthreads();
    }
    if (threadIdx.x == 0) bsum[blockIdx.x] = s[0];
}

// ---- scan step 2: exclusive scan of block sums (single block, nb <= 512) ----
__global__ __launch_bounds__(512) void k_bscan(const unsigned int* __restrict__ bsum,
                                               unsigned int* __restrict__ boff, int nb) {
    __shared__ unsigned int s[512];
    unsigned int v = (threadIdx.x < (unsigned)nb) ? bsum[threadIdx.x] : 0u;
    s[threadIdx.x] = v; __syncthreads();
    for (int off = 1; off < 512; off <<= 1) {
        unsigned int t = (threadIdx.x >= (unsigned)off) ? s[threadIdx.x - off] : 0u;
        __syncthreads();
        s[threadIdx.x] += t;
        __syncthreads();
    }
    if (threadIdx.x < (unsigned)nb) boff[threadIdx.x] = s[threadIdx.x] - v;
}

// ---- scan step 3: per-element exclusive prefix (+ sentinel S[m]=total) ----
__global__ __launch_bounds__(256) void k_scan2(const unsigned int* __restrict__ A,
                                               const unsigned int* __restrict__ boff,
                                               unsigned int* __restrict__ S, int m, int total) {
    __shared__ unsigned int s[SCAN_T];
    int tid = threadIdx.x;
    int base = blockIdx.x * SCAN_B + tid * SCAN_E;
    unsigned int t = 0;
#pragma unroll
    for (int k = 0; k < SCAN_E; ++k) { int idx = base + k; if (idx < m) t += A[idx]; }
    s[tid] = t; __syncthreads();
    unsigned int own = t;
    for (int off = 1; off < SCAN_T; off <<= 1) {
        unsigned int u = (tid >= off) ? s[tid - off] : 0u;
        __syncthreads();
        s[tid] += u;
        __syncthreads();
    }
    unsigned int run = boff[blockIdx.x] + s[tid] - own;
#pragma unroll
    for (int k = 0; k < SCAN_E; ++k) {
        int idx = base + k;
        if (idx < m) { S[idx] = run; run += A[idx]; }
    }
    if (blockIdx.x == 0 && tid == 0) S[m] = (unsigned int)total;
}

// ---- level-1 scatter, LDS-staged: edges -> bucket-grouped packed array ----
__global__ __launch_bounds__(256) void k_scat(const int* __restrict__ tgt,
                                              const int* __restrict__ src,
                                              const unsigned int* __restrict__ S,
                                              int* __restrict__ bp,
                                              int nE, int gb1, int nbins) {
    __shared__ int bpv[EPB];                 // 32 KB staged payload
    __shared__ unsigned short qid[EPB];      // 16 KB bin id per slot
    __shared__ unsigned int cur[NBCAP];      // 4 KB
    __shared__ unsigned int dif[NBCAP];      // 4 KB
    __shared__ unsigned int ps[256];
    int b = blockIdx.x, tid = threadIdx.x;
    for (int k = tid; k < NBCAP; k += 256) cur[k] = 0;
    __syncthreads();
    int e0 = b * EPB;
    int ecnt = min(EPB, nE - e0);

    // pass 1: local histogram
    for (int k = tid; k < ecnt; k += 256)
        atomicAdd(&cur[(unsigned)tgt[e0 + k] >> BSHIFT], 1u);
    __syncthreads();

    // exclusive scan over NBCAP bins, SPT per thread
    unsigned int lv[SPT]; unsigned int tsum = 0;
#pragma unroll
    for (int k = 0; k < SPT; ++k) {
        int f = SPT * tid + k;
        lv[k] = tsum; tsum += cur[f];
    }
    ps[tid] = tsum; __syncthreads();
    for (int off = 1; off < 256; off <<= 1) {
        unsigned int u = (tid >= off) ? ps[tid - off] : 0u;
        __syncthreads();
        ps[tid] += u;
        __syncthreads();
    }
    unsigned int excl = ps[tid] - tsum;
    __syncthreads();
#pragma unroll
    for (int k = 0; k < SPT; ++k) {
        int f = SPT * tid + k;
        cur[f] = excl + lv[k]; dif[f] = excl + lv[k];
    }
    __syncthreads();
    for (int q = tid; q < nbins; q += 256)
        dif[q] = S[(size_t)q * gb1 + b] - dif[q];
    __syncthreads();

    // pass 2: scatter edges into LDS, grouped by bucket
    for (int k = tid; k < ecnt; k += 256) {
        int t = tgt[e0 + k];
        int q = (unsigned)t >> BSHIFT;
        unsigned int lpos = atomicAdd(&cur[q], 1u);
        bpv[lpos] = (src[e0 + k] << BSHIFT) | (t & (BSZ - 1));
        qid[lpos] = (unsigned short)q;
    }
    __syncthreads();

    // pass 3: linear flush -> contiguous global writes per bucket
    for (int k = tid; k < ecnt; k += 256) {
        int q = qid[k];
        bp[dif[q] + k] = bpv[k];
    }
}

// ---- level-2: per-bucket fine sort with LDS-staged col flush + rowptr + dinv ----
__global__ __launch_bounds__(256) void k_bcsr(const unsigned int* __restrict__ S,
                                              const int* __restrict__ bp,
                                              unsigned int* __restrict__ rowptr,
                                              int* __restrict__ col,
                                              float* __restrict__ dinv,
                                              int n, int gb1) {
    __shared__ int lst[LSTCAP];              // 40 KB staged sorted col
    __shared__ unsigned int h[BSZ];
    __shared__ unsigned int cu[BSZ];
    __shared__ unsigned int ps[256];
    int q = blockIdx.x, tid = threadIdx.x;
    h[tid] = 0;
    __syncthreads();
    unsigned int e0 = S[(size_t)q * gb1];
    unsigned int e1 = S[(size_t)(q + 1) * gb1];
    int cnt = (int)(e1 - e0);
    for (int k = tid; k < cnt; k += 256)
        atomicAdd(&h[bp[e0 + k] & (BSZ - 1)], 1u);
    __syncthreads();
    unsigned int own = h[tid];
    ps[tid] = own; __syncthreads();
    for (int off = 1; off < 256; off <<= 1) {
        unsigned int u = (tid >= off) ? ps[tid - off] : 0u;
        __syncthreads();
        ps[tid] += u;
        __syncthreads();
    }
    unsigned int excl = ps[tid] - own;
    cu[tid] = excl;
    int i = (q << BSHIFT) + tid;
    if (i <= n) rowptr[i] = e0 + excl;       // i==n (last bucket) -> sentinel = nE
    if (i < n) {
        float d = (float)(own + 1u);
        float r = rsqrtf(d);
        r = r * (1.5f - 0.5f * d * r * r);
        dinv[i] = r;
    }
    __syncthreads();
    for (int k = tid; k < cnt; k += 256) {
        int v = bp[e0 + k];
        unsigned int pos = atomicAdd(&cu[v & (BSZ - 1)], 1u);
        lst[pos] = (unsigned)v >> BSHIFT;
    }
    __syncthreads();
    for (int k = tid; k < cnt; k += 256)
        col[e0 + k] = lst[k];
}

// ---- embeddings + h@W1, pre-scaled by dinv ----
__global__ __launch_bounds__(256) void k_embed(const int* __restrict__ x,
                                               const float* __restrict__ birth_t,
                                               const float* __restrict__ gender_t,
                                               const float* __restrict__ symp_t,
                                               const float* __restrict__ W1,
                                               const float* __restrict__ dinv,
                                               float* __restrict__ hs1, int n) {
    __shared__ float sB[BY * EMB];
    __shared__ float sG[2 * EMB];
    __shared__ float sS[NSYMP * NOPT * EMB];
    __shared__ float sW[EMB * HID];
    for (int k = threadIdx.x; k < BY * EMB; k += blockDim.x) sB[k] = birth_t[k];
    for (int k = threadIdx.x; k < 2 * EMB; k += blockDim.x) sG[k] = gender_t[k];
    for (int k = threadIdx.x; k < NSYMP * NOPT * EMB; k += blockDim.x) sS[k] = symp_t[k];
    for (int k = threadIdx.x; k < EMB * HID; k += blockDim.x) sW[k] = W1[k];
    __syncthreads();

    int i = blockIdx.x * blockDim.x + threadIdx.x;
    if (i >= n) return;

    const int* xr = x + (size_t)i * XCOLS;
    int xv[XCOLS];
#pragma unroll
    for (int k = 0; k < XCOLS; ++k) xv[k] = xr[k];

    int bi = 0;
#pragma unroll
    for (int k = 1; k < BY; ++k) if (xv[k] > xv[bi]) bi = k;
    int gi = xv[BY];

    float ssum[EMB];
#pragma unroll
    for (int k = 0; k < EMB; ++k) ssum[k] = 0.f;
#pragma unroll
    for (int j = 0; j < NSYMP; ++j) {
        const float* row = &sS[(j * NOPT + xv[BY + 1 + j]) * EMB];
#pragma unroll
        for (int k = 0; k < EMB; ++k) ssum[k] += row[k];
    }

    float h[EMB];
#pragma unroll
    for (int k = 0; k < EMB; ++k)
        h[k] = (sB[bi * EMB + k] + sG[gi * EMB + k] + ssum[k] * (1.f / 15.f)) * (1.f / 3.f);

    float hp[HID];
#pragma unroll
    for (int j = 0; j < HID; ++j) hp[j] = 0.f;
#pragma unroll
    for (int k = 0; k < EMB; ++k) {
        float hv = h[k];
#pragma unroll
        for (int j = 0; j < HID; ++j) hp[j] += hv * sW[k * HID + j];
    }

    float dv = dinv[i];
    float4* o = (float4*)(hs1 + (size_t)i * HID);
#pragma unroll
    for (int q = 0; q < 4; ++q) {
        float4 v;
        v.x = dv * hp[q * 4 + 0];
        v.y = dv * hp[q * 4 + 1];
        v.z = dv * hp[q * 4 + 2];
        v.w = dv * hp[q * 4 + 3];
        o[q] = v;
    }
}

// ---- layer 1: quartet-float4 CSR gather (4 in flight) + ELU + W2 + z ----
__global__ __launch_bounds__(256) void k_gmid4(const unsigned int* __restrict__ rowptr,
                                               const int* __restrict__ col,
                                               const float* __restrict__ A,
                                               const float* __restrict__ dinv,
                                               const float* __restrict__ W2,
                                               const float* __restrict__ b1,
                                               const float* __restrict__ Wl,
                                               float* __restrict__ z, int n) {
    __shared__ float sW[HID * HID];
    __shared__ float sb[HID];
    __shared__ float sw[HID];
    __shared__ float sh1[16][HID];
    if (threadIdx.x < HID * HID) sW[threadIdx.x] = W2[threadIdx.x];
    if (threadIdx.x < HID) { sb[threadIdx.x] = b1[threadIdx.x]; sw[threadIdx.x] = Wl[threadIdx.x]; }
    __syncthreads();

    int gg = threadIdx.x >> 4;
    int l  = threadIdx.x & 15;
    int qq = l >> 2, c = l & 3;
    int i = blockIdx.x * 16 + gg;
    bool valid = (i < n);

    unsigned int r0 = 0, r1 = 0;
    if (valid) { r0 = rowptr[i]; r1 = rowptr[i + 1]; }

    float ax = 0.f, ay = 0.f, az = 0.f, aw = 0.f;
    unsigned int e = r0;
    for (; e + 16 <= r1; e += 16) {
        int s0 = col[e + qq];
        int s1 = col[e + 4 + qq];
        int s2 = col[e + 8 + qq];
        int s3 = col[e + 12 + qq];
        float4 v0 = *(const float4*)(A + (size_t)s0 * HID + c * 4);
        float4 v1 = *(const float4*)(A + (size_t)s1 * HID + c * 4);
        float4 v2 = *(const float4*)(A + (size_t)s2 * HID + c * 4);
        float4 v3 = *(const float4*)(A + (size_t)s3 * HID + c * 4);
        ax += (v0.x + v1.x) + (v2.x + v3.x);
        ay += (v0.y + v1.y) + (v2.y + v3.y);
        az += (v0.z + v1.z) + (v2.z + v3.z);
        aw += (v0.w + v1.w) + (v2.w + v3.w);
    }
    for (; e + 4 <= r1; e += 4) {
        int s0 = col[e + qq];
        float4 v0 = *(const float4*)(A + (size_t)s0 * HID + c * 4);
        ax += v0.x; ay += v0.y; az += v0.z; aw += v0.w;
    }
    if (e + qq < r1) {
        int s0 = col[e + qq];
        float4 v0 = *(const float4*)(A + (size_t)s0 * HID + c * 4);
        ax += v0.x; ay += v0.y; az += v0.z; aw += v0.w;
    }
    ax += __shfl_xor(ax, 4, 64); ay += __shfl_xor(ay, 4, 64);
    az += __shfl_xor(az, 4, 64); aw += __shfl_xor(aw, 4, 64);
    ax += __shfl_xor(ax, 8, 64); ay += __shfl_xor(ay, 8, 64);
    az += __shfl_xor(az, 8, 64); aw += __shfl_xor(aw, 8, 64);

    float dv = valid ? dinv[i] : 0.f;
    float4 s4 = valid ? *(const float4*)(A + (size_t)i * HID + c * 4)
                      : make_float4(0.f, 0.f, 0.f, 0.f);
    float v0 = dv * (ax + s4.x) + sb[c * 4 + 0];
    float v1 = dv * (ay + s4.y) + sb[c * 4 + 1];
    float v2 = dv * (az + s4.z) + sb[c * 4 + 2];
    float v3 = dv * (aw + s4.w) + sb[c * 4 + 3];
    float h0 = (v0 > 0.f) ? v0 : expm1f(v0);
    float h1 = (v1 > 0.f) ? v1 : expm1f(v1);
    float h2 = (v2 > 0.f) ? v2 : expm1f(v2);
    float h3 = (v3 > 0.f) ? v3 : expm1f(v3);
    if (qq == 0) {
        float4 hv = make_float4(h0, h1, h2, h3);
        *(float4*)&sh1[gg][c * 4] = hv;
    }
    __syncthreads();

    float hp = 0.f;
#pragma unroll
    for (int k = 0; k < HID; ++k) hp += sh1[gg][k] * sW[k * HID + l];
    float p = dv * hp * sw[l];
#pragma unroll
    for (int off = 8; off > 0; off >>= 1) p += __shfl_xor(p, off, 64);
    if (l == 0 && valid) z[i] = p;
}

// ---- layer 2: scalar z gather, 8 partials in flight + final affine ----
__global__ __launch_bounds__(256) void k_gfin4(const unsigned int* __restrict__ rowptr,
                                               const int* __restrict__ col,
                                               const float* __restrict__ z,
                                               const float* __restrict__ dinv,
                                               const float* __restrict__ b2,
                                               const float* __restrict__ Wl,
                                               const float* __restrict__ bl,
                                               float* __restrict__ out, int n) {
    __shared__ float sc0;
    if (threadIdx.x == 0) {
        float c = 0.f;
#pragma unroll
        for (int k = 0; k < HID; ++k) c += b2[k] * Wl[k];
        sc0 = c + bl[0];
    }
    __syncthreads();

    int i = blockIdx.x * blockDim.x + threadIdx.x;
    if (i >= n) return;

    unsigned int r0 = rowptr[i];
    unsigned int r1 = rowptr[i + 1];
    float s0 = 0.f, s1 = 0.f, s2 = 0.f, s3 = 0.f;
    float s4 = 0.f, s5 = 0.f, s6 = 0.f, s7 = 0.f;
    unsigned int e = r0;
    for (; e + 8 <= r1; e += 8) {
        s0 += z[col[e + 0]]; s1 += z[col[e + 1]];
        s2 += z[col[e + 2]]; s3 += z[col[e + 3]];
        s4 += z[col[e + 4]]; s5 += z[col[e + 5]];
        s6 += z[col[e + 6]]; s7 += z[col[e + 7]];
    }
    for (; e < r1; ++e) s0 += z[col[e]];
    float s = ((s0 + s1) + (s2 + s3)) + ((s4 + s5) + (s6 + s7));
    out[i] = dinv[i] * (s + z[i]) + sc0;
}

extern "C" void kernel_launch(void* const* d_in, const int* in_sizes, int n_in,
                              void* d_out, int out_size, void* d_ws, size_t ws_size,
                              hipStream_t stream) {
    const int*   x        = (const int*)d_in[0];
    const int*   ei       = (const int*)d_in[1];   // int32 per harness conversion
    const float* birth_t  = (const float*)d_in[2];
    const float* gender_t = (const float*)d_in[3];
    const float* symp_t   = (const float*)d_in[4];
    const float* W1       = (const float*)d_in[5];
    const float* b1       = (const float*)d_in[6];
    const float* W2       = (const float*)d_in[7];
    const float* b2       = (const float*)d_in[8];
    const float* Wl       = (const float*)d_in[9];
    const float* bl       = (const float*)d_in[10];
    float*       out      = (float*)d_out;

    const int n  = in_sizes[0] / XCOLS;
    const int nE = in_sizes[1] / 2;
    const int* src = ei;
    const int* tgt = ei + nE;

    const int nbuck = (n + BSZ - 1) >> BSHIFT;            // 782
    const int gb1   = (nE + EPB - 1) / EPB;               // 782
    const int M     = nbuck * gb1;                        // ~611k
    const int nb    = (M + SCAN_B - 1) / SCAN_B;          // 75 (<=512)

    // workspace layout (256B aligned slices)
    char* ws = (char*)d_ws;
    size_t off = 0;
    auto alloc = [&](size_t bytes) { char* p = ws + off; off = (off + bytes + 255) & ~(size_t)255; return p; };
    unsigned int* H      = (unsigned int*)alloc((size_t)M * 4);
    unsigned int* S      = (unsigned int*)alloc(((size_t)M + 1) * 4);
    unsigned int* bsum   = (unsigned int*)alloc(512 * 4);
    unsigned int* boff   = (unsigned int*)alloc(512 * 4);
    int*          bp     = (int*)alloc((size_t)nE * 4);
    int*          col    = (int*)alloc((size_t)nE * 4);
    unsigned int* rowptr = (unsigned int*)alloc(((size_t)n + 1) * 4);
    float*        dinv   = (float*)alloc((size_t)n * 4);
    float*        A      = (float*)alloc((size_t)n * HID * 4);
    float*        z      = (float*)alloc((size_t)n * 4);

    const int BLK = 256;
    const int gN    = (n + BLK - 1) / BLK;
    const int gNode = (n + 15) / 16;

    k_hist <<<gb1, BLK, 0, stream>>>(tgt, H, nE, gb1, nbuck);
    k_bsum <<<nb, SCAN_T, 0, stream>>>(H, bsum, M);
    k_bscan<<<1, 512, 0, stream>>>(bsum, boff, nb);
    k_scan2<<<nb, SCAN_T, 0, stream>>>(H, boff, S, M, nE);
    k_scat <<<gb1, BLK, 0, stream>>>(tgt, src, S, bp, nE, gb1, nbuck);
    k_bcsr <<<nbuck, BLK, 0, stream>>>(S, bp, rowptr, col, dinv, n, gb1);
    k_embed<<<gN, BLK, 0, stream>>>(x, birth_t, gender_t, symp_t, W1, dinv, A, n);
    k_gmid4<<<gNode, BLK, 0, stream>>>(rowptr, col, A, dinv, W2, b1, Wl, z, n);
    k_gfin4<<<gN, BLK, 0, stream>>>(rowptr, col, z, dinv, b2, Wl, bl, out, n);
}

// Round 12
// 270.020 us; speedup vs baseline: 3.5052x; 1.1110x over previous
//
#include <hip/hip_runtime.h>
#include <hip/hip_fp16.h>
#include <math.h>

#define EMB 32
#define HID 16
#define BY 4
#define NSYMP 15
#define NOPT 3
#define XCOLS (BY + 1 + NSYMP)   // 20

#define BSHIFT 8                 // 256 nodes per tgt bucket
#define BSZ 256
#define EPB 8192                 // edges per hist/scatter block
#define NBCAP 1024               // padded bin capacity (>= nbuck=782)
#define SPT 4                    // scan items per thread in scat (1024/256)
#define LSTCAP 10240             // staged col entries per bucket

#define SCAN_T 256
#define SCAN_E 32
#define SCAN_B (SCAN_T * SCAN_E)  // 8192 elements per scan block

// ---- level-1: per-block bucket histogram (LDS atomics only) ----
__global__ __launch_bounds__(256) void k_hist(const int* __restrict__ tgt,
                                              unsigned int* __restrict__ H,
                                              int nE, int gb1, int nbins) {
    __shared__ unsigned int h[NBCAP];
    int b = blockIdx.x, tid = threadIdx.x;
    for (int k = tid; k < NBCAP; k += 256) h[k] = 0;
    __syncthreads();
    int e0 = b * EPB;
    int ecnt = min(EPB, nE - e0);
    for (int k = tid; k < ecnt; k += 256)
        atomicAdd(&h[(unsigned)tgt[e0 + k] >> BSHIFT], 1u);
    __syncthreads();
    for (int q = tid; q < nbins; q += 256) H[(size_t)q * gb1 + b] = h[q];
}

// ---- scan step 1 ----
__global__ __launch_bounds__(256) void k_bsum(const unsigned int* __restrict__ A,
                                              unsigned int* __restrict__ bsum, int m) {
    __shared__ unsigned int s[SCAN_T];
    int base = blockIdx.x * SCAN_B + threadIdx.x * SCAN_E;
    unsigned int t = 0;
#pragma unroll
    for (int k = 0; k < SCAN_E; ++k) { int idx = base + k; if (idx < m) t += A[idx]; }
    s[threadIdx.x] = t; __syncthreads();
    for (int off = SCAN_T / 2; off > 0; off >>= 1) {
        if (threadIdx.x < off) s[threadIdx.x] += s[threadIdx.x + off];
        __syncthreads();
    }
    if (threadIdx.x == 0) bsum[blockIdx.x] = s[0];
}

// ---- scan step 2 ----
__global__ __launch_bounds__(512) void k_bscan(const unsigned int* __restrict__ bsum,
                                               unsigned int* __restrict__ boff, int nb) {
    __shared__ unsigned int s[512];
    unsigned int v = (threadIdx.x < (unsigned)nb) ? bsum[threadIdx.x] : 0u;
    s[threadIdx.x] = v; __syncthreads();
    for (int off = 1; off < 512; off <<= 1) {
        unsigned int t = (threadIdx.x >= (unsigned)off) ? s[threadIdx.x - off] : 0u;
        __syncthreads();
        s[threadIdx.x] += t;
        __syncthreads();
    }
    if (threadIdx.x < (unsigned)nb) boff[threadIdx.x] = s[threadIdx.x] - v;
}

// ---- scan step 3 ----
__global__ __launch_bounds__(256) void k_scan2(const unsigned int* __restrict__ A,
                                               const unsigned int* __restrict__ boff,
                                               unsigned int* __restrict__ S, int m, int total) {
    __shared__ unsigned int s[SCAN_T];
    int tid = threadIdx.x;
    int base = blockIdx.x * SCAN_B + tid * SCAN_E;
    unsigned int t = 0;
#pragma unroll
    for (int k = 0; k < SCAN_E; ++k) { int idx = base + k; if (idx < m) t += A[idx]; }
    s[tid] = t; __syncthreads();
    unsigned int own = t;
    for (int off = 1; off < SCAN_T; off <<= 1) {
        unsigned int u = (tid >= off) ? s[tid - off] : 0u;
        __syncthreads();
        s[tid] += u;
        __syncthreads();
    }
    unsigned int run = boff[blockIdx.x] + s[tid] - own;
#pragma unroll
    for (int k = 0; k < SCAN_E; ++k) {
        int idx = base + k;
        if (idx < m) { S[idx] = run; run += A[idx]; }
    }
    if (blockIdx.x == 0 && tid == 0) S[m] = (unsigned int)total;
}

// ---- level-1 scatter, LDS-staged ----
__global__ __launch_bounds__(256) void k_scat(const int* __restrict__ tgt,
                                              const int* __restrict__ src,
                                              const unsigned int* __restrict__ S,
                                              int* __restrict__ bp,
                                              int nE, int gb1, int nbins) {
    __shared__ int bpv[EPB];
    __shared__ unsigned short qid[EPB];
    __shared__ unsigned int cur[NBCAP];
    __shared__ unsigned int dif[NBCAP];
    __shared__ unsigned int ps[256];
    int b = blockIdx.x, tid = threadIdx.x;
    for (int k = tid; k < NBCAP; k += 256) cur[k] = 0;
    __syncthreads();
    int e0 = b * EPB;
    int ecnt = min(EPB, nE - e0);

    for (int k = tid; k < ecnt; k += 256)
        atomicAdd(&cur[(unsigned)tgt[e0 + k] >> BSHIFT], 1u);
    __syncthreads();

    unsigned int lv[SPT]; unsigned int tsum = 0;
#pragma unroll
    for (int k = 0; k < SPT; ++k) {
        int f = SPT * tid + k;
        lv[k] = tsum; tsum += cur[f];
    }
    ps[tid] = tsum; __syncthreads();
    for (int off = 1; off < 256; off <<= 1) {
        unsigned int u = (tid >= off) ? ps[tid - off] : 0u;
        __syncthreads();
        ps[tid] += u;
        __syncthreads();
    }
    unsigned int excl = ps[tid] - tsum;
    __syncthreads();
#pragma unroll
    for (int k = 0; k < SPT; ++k) {
        int f = SPT * tid + k;
        cur[f] = excl + lv[k]; dif[f] = excl + lv[k];
    }
    __syncthreads();
    for (int q = tid; q < nbins; q += 256)
        dif[q] = S[(size_t)q * gb1 + b] - dif[q];
    __syncthreads();

    for (int k = tid; k < ecnt; k += 256) {
        int t = tgt[e0 + k];
        int q = (unsigned)t >> BSHIFT;
        unsigned int lpos = atomicAdd(&cur[q], 1u);
        bpv[lpos] = (src[e0 + k] << BSHIFT) | (t & (BSZ - 1));
        qid[lpos] = (unsigned short)q;
    }
    __syncthreads();

    for (int k = tid; k < ecnt; k += 256) {
        int q = qid[k];
        bp[dif[q] + k] = bpv[k];
    }
}

// ---- level-2: per-bucket fine sort, LDS-staged col flush + rowptr + dinv ----
__global__ __launch_bounds__(256) void k_bcsr(const unsigned int* __restrict__ S,
                                              const int* __restrict__ bp,
                                              unsigned int* __restrict__ rowptr,
                                              int* __restrict__ col,
                                              float* __restrict__ dinv,
                                              int n, int gb1) {
    __shared__ int lst[LSTCAP];
    __shared__ unsigned int h[BSZ];
    __shared__ unsigned int cu[BSZ];
    __shared__ unsigned int ps[256];
    int q = blockIdx.x, tid = threadIdx.x;
    h[tid] = 0;
    __syncthreads();
    unsigned int e0 = S[(size_t)q * gb1];
    unsigned int e1 = S[(size_t)(q + 1) * gb1];
    int cnt = (int)(e1 - e0);
    for (int k = tid; k < cnt; k += 256)
        atomicAdd(&h[bp[e0 + k] & (BSZ - 1)], 1u);
    __syncthreads();
    unsigned int own = h[tid];
    ps[tid] = own; __syncthreads();
    for (int off = 1; off < 256; off <<= 1) {
        unsigned int u = (tid >= off) ? ps[tid - off] : 0u;
        __syncthreads();
        ps[tid] += u;
        __syncthreads();
    }
    unsigned int excl = ps[tid] - own;
    cu[tid] = excl;
    int i = (q << BSHIFT) + tid;
    if (i <= n) rowptr[i] = e0 + excl;
    if (i < n) {
        float d = (float)(own + 1u);
        float r = rsqrtf(d);
        r = r * (1.5f - 0.5f * d * r * r);
        dinv[i] = r;
    }
    __syncthreads();
    for (int k = tid; k < cnt; k += 256) {
        int v = bp[e0 + k];
        unsigned int pos = atomicAdd(&cu[v & (BSZ - 1)], 1u);
        lst[pos] = (unsigned)v >> BSHIFT;
    }
    __syncthreads();
    for (int k = tid; k < cnt; k += 256)
        col[e0 + k] = lst[k];
}

// ---- embeddings + h@W1, pre-scaled by dinv, stored as fp16 rows (32 B) ----
__global__ __launch_bounds__(256) void k_embed(const int* __restrict__ x,
                                               const float* __restrict__ birth_t,
                                               const float* __restrict__ gender_t,
                                               const float* __restrict__ symp_t,
                                               const float* __restrict__ W1,
                                               const float* __restrict__ dinv,
                                               __half* __restrict__ A16, int n) {
    __shared__ float sB[BY * EMB];
    __shared__ float sG[2 * EMB];
    __shared__ float sS[NSYMP * NOPT * EMB];
    __shared__ float sW[EMB * HID];
    for (int k = threadIdx.x; k < BY * EMB; k += blockDim.x) sB[k] = birth_t[k];
    for (int k = threadIdx.x; k < 2 * EMB; k += blockDim.x) sG[k] = gender_t[k];
    for (int k = threadIdx.x; k < NSYMP * NOPT * EMB; k += blockDim.x) sS[k] = symp_t[k];
    for (int k = threadIdx.x; k < EMB * HID; k += blockDim.x) sW[k] = W1[k];
    __syncthreads();

    int i = blockIdx.x * blockDim.x + threadIdx.x;
    if (i >= n) return;

    const int* xr = x + (size_t)i * XCOLS;
    int xv[XCOLS];
#pragma unroll
    for (int k = 0; k < XCOLS; ++k) xv[k] = xr[k];

    int bi = 0;
#pragma unroll
    for (int k = 1; k < BY; ++k) if (xv[k] > xv[bi]) bi = k;
    int gi = xv[BY];

    float ssum[EMB];
#pragma unroll
    for (int k = 0; k < EMB; ++k) ssum[k] = 0.f;
#pragma unroll
    for (int j = 0; j < NSYMP; ++j) {
        const float* row = &sS[(j * NOPT + xv[BY + 1 + j]) * EMB];
#pragma unroll
        for (int k = 0; k < EMB; ++k) ssum[k] += row[k];
    }

    float h[EMB];
#pragma unroll
    for (int k = 0; k < EMB; ++k)
        h[k] = (sB[bi * EMB + k] + sG[gi * EMB + k] + ssum[k] * (1.f / 15.f)) * (1.f / 3.f);

    float hp[HID];
#pragma unroll
    for (int j = 0; j < HID; ++j) hp[j] = 0.f;
#pragma unroll
    for (int k = 0; k < EMB; ++k) {
        float hv = h[k];
#pragma unroll
        for (int j = 0; j < HID; ++j) hp[j] += hv * sW[k * HID + j];
    }

    float dv = dinv[i];
    __half2 t2[8];
#pragma unroll
    for (int j = 0; j < 8; ++j)
        t2[j] = __floats2half2_rn(dv * hp[2 * j], dv * hp[2 * j + 1]);
    uint4* o = (uint4*)(A16 + (size_t)i * HID);
    o[0] = *(uint4*)&t2[0];
    o[1] = *(uint4*)&t2[4];
}

// ---- layer 1: lane-pair fp16 CSR gather (8 edges / group-step, 2 in flight)
//      + ELU + W2 + z = hs2 . Wl ----
__global__ __launch_bounds__(256) void k_gmid5(const unsigned int* __restrict__ rowptr,
                                               const int* __restrict__ col,
                                               const __half* __restrict__ A16,
                                               const float* __restrict__ dinv,
                                               const float* __restrict__ W2,
                                               const float* __restrict__ b1,
                                               const float* __restrict__ Wl,
                                               float* __restrict__ z, int n) {
    __shared__ float sW[HID * HID];
    __shared__ float sb[HID];
    __shared__ float sw[HID];
    __shared__ float sAcc[16][HID];
    if (threadIdx.x < HID * HID) sW[threadIdx.x] = W2[threadIdx.x];
    if (threadIdx.x < HID) { sb[threadIdx.x] = b1[threadIdx.x]; sw[threadIdx.x] = Wl[threadIdx.x]; }
    __syncthreads();

    int gg = threadIdx.x >> 4;
    int l  = threadIdx.x & 15;
    int p  = l >> 1;                 // edge slot 0..7
    int hc = l & 1;                  // row half (8 halves = 16 B)
    int i = blockIdx.x * 16 + gg;
    bool valid = (i < n);

    unsigned int r0 = 0, r1 = 0;
    if (valid) { r0 = rowptr[i]; r1 = rowptr[i + 1]; }

    float a[8];
#pragma unroll
    for (int k = 0; k < 8; ++k) a[k] = 0.f;

    unsigned int e = r0;
    for (; e + 16 <= r1; e += 16) {
        int s0 = col[e + p];
        int s1 = col[e + 8 + p];
        uint4 raw0 = *((const uint4*)(A16 + (size_t)s0 * HID) + hc);
        uint4 raw1 = *((const uint4*)(A16 + (size_t)s1 * HID) + hc);
        const __half2* h0 = (const __half2*)&raw0;
        const __half2* h1 = (const __half2*)&raw1;
#pragma unroll
        for (int k = 0; k < 4; ++k) {
            float2 f0 = __half22float2(h0[k]);
            float2 f1 = __half22float2(h1[k]);
            a[2 * k]     += f0.x + f1.x;
            a[2 * k + 1] += f0.y + f1.y;
        }
    }
    for (; e + 8 <= r1; e += 8) {
        int s0 = col[e + p];
        uint4 raw0 = *((const uint4*)(A16 + (size_t)s0 * HID) + hc);
        const __half2* h0 = (const __half2*)&raw0;
#pragma unroll
        for (int k = 0; k < 4; ++k) {
            float2 f0 = __half22float2(h0[k]);
            a[2 * k]     += f0.x;
            a[2 * k + 1] += f0.y;
        }
    }
    if (e + p < r1) {
        int s0 = col[e + p];
        uint4 raw0 = *((const uint4*)(A16 + (size_t)s0 * HID) + hc);
        const __half2* h0 = (const __half2*)&raw0;
#pragma unroll
        for (int k = 0; k < 4; ++k) {
            float2 f0 = __half22float2(h0[k]);
            a[2 * k]     += f0.x;
            a[2 * k + 1] += f0.y;
        }
    }
    // reduce across edge-slot bits (lane bits 1..3); comps stay split by hc
#pragma unroll
    for (int k = 0; k < 8; ++k) {
        a[k] += __shfl_xor(a[k], 2, 64);
        a[k] += __shfl_xor(a[k], 4, 64);
        a[k] += __shfl_xor(a[k], 8, 64);
    }
    if (l < 2) {
        float4* d0 = (float4*)&sAcc[gg][hc * 8];
        d0[0] = make_float4(a[0], a[1], a[2], a[3]);
        d0[1] = make_float4(a[4], a[5], a[6], a[7]);
    }
    __syncthreads();

    float dv = valid ? dinv[i] : 0.f;
    float self = valid ? __half2float(A16[(size_t)i * HID + l]) : 0.f;
    float v = dv * (sAcc[gg][l] + self) + sb[l];
    float h1 = (v > 0.f) ? v : expm1f(v);

    int lanebase = (threadIdx.x & 63) & ~15;
    float hp = 0.f;
#pragma unroll
    for (int k = 0; k < HID; ++k)
        hp += __shfl(h1, lanebase + k, 64) * sW[k * HID + l];
    float pz = dv * hp * sw[l];
#pragma unroll
    for (int off = 8; off > 0; off >>= 1) pz += __shfl_xor(pz, off, 64);
    if (l == 0 && valid) z[i] = pz;
}

// ---- layer 2: scalar z gather, 8 partials in flight + final affine ----
__global__ __launch_bounds__(256) void k_gfin4(const unsigned int* __restrict__ rowptr,
                                               const int* __restrict__ col,
                                               const float* __restrict__ z,
                                               const float* __restrict__ dinv,
                                               const float* __restrict__ b2,
                                               const float* __restrict__ Wl,
                                               const float* __restrict__ bl,
                                               float* __restrict__ out, int n) {
    __shared__ float sc0;
    if (threadIdx.x == 0) {
        float c = 0.f;
#pragma unroll
        for (int k = 0; k < HID; ++k) c += b2[k] * Wl[k];
        sc0 = c + bl[0];
    }
    __syncthreads();

    int i = blockIdx.x * blockDim.x + threadIdx.x;
    if (i >= n) return;

    unsigned int r0 = rowptr[i];
    unsigned int r1 = rowptr[i + 1];
    float s0 = 0.f, s1 = 0.f, s2 = 0.f, s3 = 0.f;
    float s4 = 0.f, s5 = 0.f, s6 = 0.f, s7 = 0.f;
    unsigned int e = r0;
    for (; e + 8 <= r1; e += 8) {
        s0 += z[col[e + 0]]; s1 += z[col[e + 1]];
        s2 += z[col[e + 2]]; s3 += z[col[e + 3]];
        s4 += z[col[e + 4]]; s5 += z[col[e + 5]];
        s6 += z[col[e + 6]]; s7 += z[col[e + 7]];
    }
    for (; e < r1; ++e) s0 += z[col[e]];
    float s = ((s0 + s1) + (s2 + s3)) + ((s4 + s5) + (s6 + s7));
    out[i] = dinv[i] * (s + z[i]) + sc0;
}

extern "C" void kernel_launch(void* const* d_in, const int* in_sizes, int n_in,
                              void* d_out, int out_size, void* d_ws, size_t ws_size,
                              hipStream_t stream) {
    const int*   x        = (const int*)d_in[0];
    const int*   ei       = (const int*)d_in[1];   // int32 per harness conversion
    const float* birth_t  = (const float*)d_in[2];
    const float* gender_t = (const float*)d_in[3];
    const float* symp_t   = (const float*)d_in[4];
    const float* W1       = (const float*)d_in[5];
    const float* b1       = (const float*)d_in[6];
    const float* W2       = (const float*)d_in[7];
    const float* b2       = (const float*)d_in[8];
    const float* Wl       = (const float*)d_in[9];
    const float* bl       = (const float*)d_in[10];
    float*       out      = (float*)d_out;

    const int n  = in_sizes[0] / XCOLS;
    const int nE = in_sizes[1] / 2;
    const int* src = ei;
    const int* tgt = ei + nE;

    const int nbuck = (n + BSZ - 1) >> BSHIFT;            // 782
    const int gb1   = (nE + EPB - 1) / EPB;               // 782
    const int M     = nbuck * gb1;                        // ~611k
    const int nb    = (M + SCAN_B - 1) / SCAN_B;          // 75 (<=512)

    // workspace layout (256B aligned slices)
    char* ws = (char*)d_ws;
    size_t off = 0;
    auto alloc = [&](size_t bytes) { char* p = ws + off; off = (off + bytes + 255) & ~(size_t)255; return p; };
    unsigned int* H      = (unsigned int*)alloc((size_t)M * 4);
    unsigned int* S      = (unsigned int*)alloc(((size_t)M + 1) * 4);
    unsigned int* bsum   = (unsigned int*)alloc(512 * 4);
    unsigned int* boff   = (unsigned int*)alloc(512 * 4);
    int*          bp     = (int*)alloc((size_t)nE * 4);
    int*          col    = (int*)alloc((size_t)nE * 4);
    unsigned int* rowptr = (unsigned int*)alloc(((size_t)n + 1) * 4);
    float*        dinv   = (float*)alloc((size_t)n * 4);
    __half*       A16    = (__half*)alloc((size_t)n * HID * 2);
    float*        z      = (float*)alloc((size_t)n * 4);

    const int BLK = 256;
    const int gN    = (n + BLK - 1) / BLK;
    const int gNode = (n + 15) / 16;

    k_hist <<<gb1, BLK, 0, stream>>>(tgt, H, nE, gb1, nbuck);
    k_bsum <<<nb, SCAN_T, 0, stream>>>(H, bsum, M);
    k_bscan<<<1, 512, 0, stream>>>(bsum, boff, nb);
    k_scan2<<<nb, SCAN_T, 0, stream>>>(H, boff, S, M, nE);
    k_scat <<<gb1, BLK, 0, stream>>>(tgt, src, S, bp, nE, gb1, nbuck);
    k_bcsr <<<nbuck, BLK, 0, stream>>>(S, bp, rowptr, col, dinv, n, gb1);
    k_embed<<<gN, BLK, 0, stream>>>(x, birth_t, gender_t, symp_t, W1, dinv, A16, n);
    k_gmid5<<<gNode, BLK, 0, stream>>>(rowptr, col, A16, dinv, W2, b1, Wl, z, n);
    k_gfin4<<<gN, BLK, 0, stream>>>(rowptr, col, z, dinv, b2, Wl, bl, out, n);
}

// Round 13
// 258.873 us; speedup vs baseline: 3.6561x; 1.0431x over previous
//
#include <hip/hip_runtime.h>
#include <hip/hip_fp16.h>
#include <math.h>

#define EMB 32
#define HID 16
#define BY 4
#define NSYMP 15
#define NOPT 3
#define XCOLS (BY + 1 + NSYMP)   // 20

#define BSHIFT 8                 // 256 nodes per tgt bucket
#define BSZ 256
#define EPB 4096                 // edges per hist/scatter block (33 KB LDS -> 4 blocks/CU)
#define NBCAP 1024               // padded bin capacity (>= nbuck=782)
#define SPT 4                    // scan items per thread in scat (1024/256)
#define LSTCAP 10240             // staged col entries per bucket

#define SCAN_T 256
#define SCAN_E 32
#define SCAN_B (SCAN_T * SCAN_E)  // 8192 elements per scan block

__device__ __forceinline__ unsigned int wave_incl_scan(unsigned int v, int lane) {
#pragma unroll
    for (int off = 1; off < 64; off <<= 1) {
        unsigned int u = __shfl_up(v, off, 64);
        if (lane >= off) v += u;
    }
    return v;
}

// ---- level-1: per-block bucket histogram (LDS atomics only) ----
__global__ __launch_bounds__(256) void k_hist(const int* __restrict__ tgt,
                                              unsigned int* __restrict__ H,
                                              int nE, int gb1, int nbins) {
    __shared__ unsigned int h[NBCAP];
    int b = blockIdx.x, tid = threadIdx.x;
    for (int k = tid; k < NBCAP; k += 256) h[k] = 0;
    __syncthreads();
    int e0 = b * EPB;
    int ecnt = min(EPB, nE - e0);
    for (int k = tid; k < ecnt; k += 256)
        atomicAdd(&h[(unsigned)tgt[e0 + k] >> BSHIFT], 1u);
    __syncthreads();
    for (int q = tid; q < nbins; q += 256) H[(size_t)q * gb1 + b] = h[q];
}

// ---- scan step 1 ----
__global__ __launch_bounds__(256) void k_bsum(const unsigned int* __restrict__ A,
                                              unsigned int* __restrict__ bsum, int m) {
    __shared__ unsigned int s[SCAN_T];
    int base = blockIdx.x * SCAN_B + threadIdx.x * SCAN_E;
    unsigned int t = 0;
#pragma unroll
    for (int k = 0; k < SCAN_E; ++k) { int idx = base + k; if (idx < m) t += A[idx]; }
    s[threadIdx.x] = t; __syncthreads();
    for (int off = SCAN_T / 2; off > 0; off >>= 1) {
        if (threadIdx.x < off) s[threadIdx.x] += s[threadIdx.x + off];
        __syncthreads();
    }
    if (threadIdx.x == 0) bsum[blockIdx.x] = s[0];
}

// ---- scan step 2 ----
__global__ __launch_bounds__(512) void k_bscan(const unsigned int* __restrict__ bsum,
                                               unsigned int* __restrict__ boff, int nb) {
    __shared__ unsigned int s[512];
    unsigned int v = (threadIdx.x < (unsigned)nb) ? bsum[threadIdx.x] : 0u;
    s[threadIdx.x] = v; __syncthreads();
    for (int off = 1; off < 512; off <<= 1) {
        unsigned int t = (threadIdx.x >= (unsigned)off) ? s[threadIdx.x - off] : 0u;
        __syncthreads();
        s[threadIdx.x] += t;
        __syncthreads();
    }
    if (threadIdx.x < (unsigned)nb) boff[threadIdx.x] = s[threadIdx.x] - v;
}

// ---- scan step 3 ----
__global__ __launch_bounds__(256) void k_scan2(const unsigned int* __restrict__ A,
                                               const unsigned int* __restrict__ boff,
                                               unsigned int* __restrict__ S, int m, int total) {
    __shared__ unsigned int s[SCAN_T];
    int tid = threadIdx.x;
    int base = blockIdx.x * SCAN_B + tid * SCAN_E;
    unsigned int t = 0;
#pragma unroll
    for (int k = 0; k < SCAN_E; ++k) { int idx = base + k; if (idx < m) t += A[idx]; }
    s[tid] = t; __syncthreads();
    unsigned int own = t;
    for (int off = 1; off < SCAN_T; off <<= 1) {
        unsigned int u = (tid >= off) ? s[tid - off] : 0u;
        __syncthreads();
        s[tid] += u;
        __syncthreads();
    }
    unsigned int run = boff[blockIdx.x] + s[tid] - own;
#pragma unroll
    for (int k = 0; k < SCAN_E; ++k) {
        int idx = base + k;
        if (idx < m) { S[idx] = run; run += A[idx]; }
    }
    if (blockIdx.x == 0 && tid == 0) S[m] = (unsigned int)total;
}

// ---- level-1 scatter, LDS-staged, wave-shfl scan ----
__global__ __launch_bounds__(256) void k_scat(const int* __restrict__ tgt,
                                              const int* __restrict__ src,
                                              const unsigned int* __restrict__ S,
                                              int* __restrict__ bp,
                                              int nE, int gb1, int nbins) {
    __shared__ int bpv[EPB];                 // 16 KB
    __shared__ unsigned short qid[EPB];      // 8 KB
    __shared__ unsigned int cur[NBCAP];      // 4 KB
    __shared__ unsigned int dif[NBCAP];      // 4 KB
    __shared__ unsigned int wsum[4];
    int b = blockIdx.x, tid = threadIdx.x;
    int lane = tid & 63, wid = tid >> 6;
    for (int k = tid; k < NBCAP; k += 256) cur[k] = 0;
    __syncthreads();
    int e0 = b * EPB;
    int ecnt = min(EPB, nE - e0);

    // pass 1: local histogram
    for (int k = tid; k < ecnt; k += 256)
        atomicAdd(&cur[(unsigned)tgt[e0 + k] >> BSHIFT], 1u);
    __syncthreads();

    // exclusive scan over NBCAP bins: per-thread serial + wave shfl + 4-way combine
    unsigned int lv[SPT]; unsigned int tsum = 0;
#pragma unroll
    for (int k = 0; k < SPT; ++k) {
        int f = SPT * tid + k;
        lv[k] = tsum; tsum += cur[f];
    }
    unsigned int incl = wave_incl_scan(tsum, lane);
    if (lane == 63) wsum[wid] = incl;
    __syncthreads();
    unsigned int woff = 0;
    for (int w = 0; w < wid; ++w) woff += wsum[w];
    unsigned int excl = woff + incl - tsum;
    __syncthreads();   // everyone done reading cur as histogram
#pragma unroll
    for (int k = 0; k < SPT; ++k) {
        int f = SPT * tid + k;
        cur[f] = excl + lv[k]; dif[f] = excl + lv[k];
    }
    __syncthreads();
    for (int q = tid; q < nbins; q += 256)
        dif[q] = S[(size_t)q * gb1 + b] - dif[q];
    __syncthreads();

    // pass 2: scatter edges into LDS, grouped by bucket
    for (int k = tid; k < ecnt; k += 256) {
        int t = tgt[e0 + k];
        int q = (unsigned)t >> BSHIFT;
        unsigned int lpos = atomicAdd(&cur[q], 1u);
        bpv[lpos] = (src[e0 + k] << BSHIFT) | (t & (BSZ - 1));
        qid[lpos] = (unsigned short)q;
    }
    __syncthreads();

    // pass 3: linear flush -> contiguous global writes per bucket
    for (int k = tid; k < ecnt; k += 256) {
        int q = qid[k];
        bp[dif[q] + k] = bpv[k];
    }
}

// ---- level-2: per-bucket fine sort, wave-shfl scan, LDS-staged col flush ----
__global__ __launch_bounds__(256) void k_bcsr(const unsigned int* __restrict__ S,
                                              const int* __restrict__ bp,
                                              unsigned int* __restrict__ rowptr,
                                              int* __restrict__ col,
                                              float* __restrict__ dinv,
                                              int n, int gb1) {
    __shared__ int lst[LSTCAP];
    __shared__ unsigned int h[BSZ];
    __shared__ unsigned int cu[BSZ];
    __shared__ unsigned int wsum[4];
    int q = blockIdx.x, tid = threadIdx.x;
    int lane = tid & 63, wid = tid >> 6;
    h[tid] = 0;
    __syncthreads();
    unsigned int e0 = S[(size_t)q * gb1];
    unsigned int e1 = S[(size_t)(q + 1) * gb1];
    int cnt = (int)(e1 - e0);
    for (int k = tid; k < cnt; k += 256)
        atomicAdd(&h[bp[e0 + k] & (BSZ - 1)], 1u);
    __syncthreads();
    unsigned int own = h[tid];
    unsigned int incl = wave_incl_scan(own, lane);
    if (lane == 63) wsum[wid] = incl;
    __syncthreads();
    unsigned int woff = 0;
    for (int w = 0; w < wid; ++w) woff += wsum[w];
    unsigned int excl = woff + incl - own;
    cu[tid] = excl;
    int i = (q << BSHIFT) + tid;
    if (i <= n) rowptr[i] = e0 + excl;
    if (i < n) {
        float d = (float)(own + 1u);
        float r = rsqrtf(d);
        r = r * (1.5f - 0.5f * d * r * r);
        dinv[i] = r;
    }
    __syncthreads();
    for (int k = tid; k < cnt; k += 256) {
        int v = bp[e0 + k];
        unsigned int pos = atomicAdd(&cu[v & (BSZ - 1)], 1u);
        lst[pos] = (unsigned)v >> BSHIFT;
    }
    __syncthreads();
    for (int k = tid; k < cnt; k += 256)
        col[e0 + k] = lst[k];
}

// ---- embeddings + h@W1, pre-scaled by dinv, stored as fp16 rows (32 B) ----
__global__ __launch_bounds__(256) void k_embed(const int* __restrict__ x,
                                               const float* __restrict__ birth_t,
                                               const float* __restrict__ gender_t,
                                               const float* __restrict__ symp_t,
                                               const float* __restrict__ W1,
                                               const float* __restrict__ dinv,
                                               __half* __restrict__ A16, int n) {
    __shared__ float sB[BY * EMB];
    __shared__ float sG[2 * EMB];
    __shared__ float sS[NSYMP * NOPT * EMB];
    __shared__ float sW[EMB * HID];
    for (int k = threadIdx.x; k < BY * EMB; k += blockDim.x) sB[k] = birth_t[k];
    for (int k = threadIdx.x; k < 2 * EMB; k += blockDim.x) sG[k] = gender_t[k];
    for (int k = threadIdx.x; k < NSYMP * NOPT * EMB; k += blockDim.x) sS[k] = symp_t[k];
    for (int k = threadIdx.x; k < EMB * HID; k += blockDim.x) sW[k] = W1[k];
    __syncthreads();

    int i = blockIdx.x * blockDim.x + threadIdx.x;
    if (i >= n) return;

    const int* xr = x + (size_t)i * XCOLS;
    int xv[XCOLS];
#pragma unroll
    for (int k = 0; k < XCOLS; ++k) xv[k] = xr[k];

    int bi = 0;
#pragma unroll
    for (int k = 1; k < BY; ++k) if (xv[k] > xv[bi]) bi = k;
    int gi = xv[BY];

    float ssum[EMB];
#pragma unroll
    for (int k = 0; k < EMB; ++k) ssum[k] = 0.f;
#pragma unroll
    for (int j = 0; j < NSYMP; ++j) {
        const float* row = &sS[(j * NOPT + xv[BY + 1 + j]) * EMB];
#pragma unroll
        for (int k = 0; k < EMB; ++k) ssum[k] += row[k];
    }

    float h[EMB];
#pragma unroll
    for (int k = 0; k < EMB; ++k)
        h[k] = (sB[bi * EMB + k] + sG[gi * EMB + k] + ssum[k] * (1.f / 15.f)) * (1.f / 3.f);

    float hp[HID];
#pragma unroll
    for (int j = 0; j < HID; ++j) hp[j] = 0.f;
#pragma unroll
    for (int k = 0; k < EMB; ++k) {
        float hv = h[k];
#pragma unroll
        for (int j = 0; j < HID; ++j) hp[j] += hv * sW[k * HID + j];
    }

    float dv = dinv[i];
    __half2 t2[8];
#pragma unroll
    for (int j = 0; j < 8; ++j)
        t2[j] = __floats2half2_rn(dv * hp[2 * j], dv * hp[2 * j + 1]);
    uint4* o = (uint4*)(A16 + (size_t)i * HID);
    o[0] = *(uint4*)&t2[0];
    o[1] = *(uint4*)&t2[4];
}

// ---- layer 1: lane-pair fp16 CSR gather + ELU + W2 + z = hs2 . Wl ----
__global__ __launch_bounds__(256) void k_gmid5(const unsigned int* __restrict__ rowptr,
                                               const int* __restrict__ col,
                                               const __half* __restrict__ A16,
                                               const float* __restrict__ dinv,
                                               const float* __restrict__ W2,
                                               const float* __restrict__ b1,
                                               const float* __restrict__ Wl,
                                               float* __restrict__ z, int n) {
    __shared__ float sW[HID * HID];
    __shared__ float sb[HID];
    __shared__ float sw[HID];
    __shared__ float sAcc[16][HID];
    if (threadIdx.x < HID * HID) sW[threadIdx.x] = W2[threadIdx.x];
    if (threadIdx.x < HID) { sb[threadIdx.x] = b1[threadIdx.x]; sw[threadIdx.x] = Wl[threadIdx.x]; }
    __syncthreads();

    int gg = threadIdx.x >> 4;
    int l  = threadIdx.x & 15;
    int p  = l >> 1;
    int hc = l & 1;
    int i = blockIdx.x * 16 + gg;
    bool valid = (i < n);

    unsigned int r0 = 0, r1 = 0;
    if (valid) { r0 = rowptr[i]; r1 = rowptr[i + 1]; }

    float a[8];
#pragma unroll
    for (int k = 0; k < 8; ++k) a[k] = 0.f;

    unsigned int e = r0;
    for (; e + 16 <= r1; e += 16) {
        int s0 = col[e + p];
        int s1 = col[e + 8 + p];
        uint4 raw0 = *((const uint4*)(A16 + (size_t)s0 * HID) + hc);
        uint4 raw1 = *((const uint4*)(A16 + (size_t)s1 * HID) + hc);
        const __half2* h0 = (const __half2*)&raw0;
        const __half2* h1 = (const __half2*)&raw1;
#pragma unroll
        for (int k = 0; k < 4; ++k) {
            float2 f0 = __half22float2(h0[k]);
            float2 f1 = __half22float2(h1[k]);
            a[2 * k]     += f0.x + f1.x;
            a[2 * k + 1] += f0.y + f1.y;
        }
    }
    for (; e + 8 <= r1; e += 8) {
        int s0 = col[e + p];
        uint4 raw0 = *((const uint4*)(A16 + (size_t)s0 * HID) + hc);
        const __half2* h0 = (const __half2*)&raw0;
#pragma unroll
        for (int k = 0; k < 4; ++k) {
            float2 f0 = __half22float2(h0[k]);
            a[2 * k]     += f0.x;
            a[2 * k + 1] += f0.y;
        }
    }
    if (e + p < r1) {
        int s0 = col[e + p];
        uint4 raw0 = *((const uint4*)(A16 + (size_t)s0 * HID) + hc);
        const __half2* h0 = (const __half2*)&raw0;
#pragma unroll
        for (int k = 0; k < 4; ++k) {
            float2 f0 = __half22float2(h0[k]);
            a[2 * k]     += f0.x;
            a[2 * k + 1] += f0.y;
        }
    }
#pragma unroll
    for (int k = 0; k < 8; ++k) {
        a[k] += __shfl_xor(a[k], 2, 64);
        a[k] += __shfl_xor(a[k], 4, 64);
        a[k] += __shfl_xor(a[k], 8, 64);
    }
    if (l < 2) {
        float4* d0 = (float4*)&sAcc[gg][hc * 8];
        d0[0] = make_float4(a[0], a[1], a[2], a[3]);
        d0[1] = make_float4(a[4], a[5], a[6], a[7]);
    }
    __syncthreads();

    float dv = valid ? dinv[i] : 0.f;
    float self = valid ? __half2float(A16[(size_t)i * HID + l]) : 0.f;
    float v = dv * (sAcc[gg][l] + self) + sb[l];
    float h1 = (v > 0.f) ? v : expm1f(v);

    int lanebase = (threadIdx.x & 63) & ~15;
    float hp = 0.f;
#pragma unroll
    for (int k = 0; k < HID; ++k)
        hp += __shfl(h1, lanebase + k, 64) * sW[k * HID + l];
    float pz = dv * hp * sw[l];
#pragma unroll
    for (int off = 8; off > 0; off >>= 1) pz += __shfl_xor(pz, off, 64);
    if (l == 0 && valid) z[i] = pz;
}

// ---- layer 2: scalar z gather, 8 partials in flight + final affine ----
__global__ __launch_bounds__(256) void k_gfin4(const unsigned int* __restrict__ rowptr,
                                               const int* __restrict__ col,
                                               const float* __restrict__ z,
                                               const float* __restrict__ dinv,
                                               const float* __restrict__ b2,
                                               const float* __restrict__ Wl,
                                               const float* __restrict__ bl,
                                               float* __restrict__ out, int n) {
    __shared__ float sc0;
    if (threadIdx.x == 0) {
        float c = 0.f;
#pragma unroll
        for (int k = 0; k < HID; ++k) c += b2[k] * Wl[k];
        sc0 = c + bl[0];
    }
    __syncthreads();

    int i = blockIdx.x * blockDim.x + threadIdx.x;
    if (i >= n) return;

    unsigned int r0 = rowptr[i];
    unsigned int r1 = rowptr[i + 1];
    float s0 = 0.f, s1 = 0.f, s2 = 0.f, s3 = 0.f;
    float s4 = 0.f, s5 = 0.f, s6 = 0.f, s7 = 0.f;
    unsigned int e = r0;
    for (; e + 8 <= r1; e += 8) {
        s0 += z[col[e + 0]]; s1 += z[col[e + 1]];
        s2 += z[col[e + 2]]; s3 += z[col[e + 3]];
        s4 += z[col[e + 4]]; s5 += z[col[e + 5]];
        s6 += z[col[e + 6]]; s7 += z[col[e + 7]];
    }
    for (; e < r1; ++e) s0 += z[col[e]];
    float s = ((s0 + s1) + (s2 + s3)) + ((s4 + s5) + (s6 + s7));
    out[i] = dinv[i] * (s + z[i]) + sc0;
}

extern "C" void kernel_launch(void* const* d_in, const int* in_sizes, int n_in,
                              void* d_out, int out_size, void* d_ws, size_t ws_size,
                              hipStream_t stream) {
    const int*   x        = (const int*)d_in[0];
    const int*   ei       = (const int*)d_in[1];   // int32 per harness conversion
    const float* birth_t  = (const float*)d_in[2];
    const float* gender_t = (const float*)d_in[3];
    const float* symp_t   = (const float*)d_in[4];
    const float* W1       = (const float*)d_in[5];
    const float* b1       = (const float*)d_in[6];
    const float* W2       = (const float*)d_in[7];
    const float* b2       = (const float*)d_in[8];
    const float* Wl       = (const float*)d_in[9];
    const float* bl       = (const float*)d_in[10];
    float*       out      = (float*)d_out;

    const int n  = in_sizes[0] / XCOLS;
    const int nE = in_sizes[1] / 2;
    const int* src = ei;
    const int* tgt = ei + nE;

    const int nbuck = (n + BSZ - 1) >> BSHIFT;            // 782
    const int gb1   = (nE + EPB - 1) / EPB;               // 1563
    const int M     = nbuck * gb1;                        // ~1.22M
    const int nb    = (M + SCAN_B - 1) / SCAN_B;          // ~150 (<=512)

    // workspace layout (256B aligned slices)
    char* ws = (char*)d_ws;
    size_t off = 0;
    auto alloc = [&](size_t bytes) { char* p = ws + off; off = (off + bytes + 255) & ~(size_t)255; return p; };
    unsigned int* H      = (unsigned int*)alloc((size_t)M * 4);
    unsigned int* S      = (unsigned int*)alloc(((size_t)M + 1) * 4);
    unsigned int* bsum   = (unsigned int*)alloc(512 * 4);
    unsigned int* boff   = (unsigned int*)alloc(512 * 4);
    int*          bp     = (int*)alloc((size_t)nE * 4);
    int*          col    = (int*)alloc((size_t)nE * 4);
    unsigned int* rowptr = (unsigned int*)alloc(((size_t)n + 1) * 4);
    float*        dinv   = (float*)alloc((size_t)n * 4);
    __half*       A16    = (__half*)alloc((size_t)n * HID * 2);
    float*        z      = (float*)alloc((size_t)n * 4);

    const int BLK = 256;
    const int gN    = (n + BLK - 1) / BLK;
    const int gNode = (n + 15) / 16;

    k_hist <<<gb1, BLK, 0, stream>>>(tgt, H, nE, gb1, nbuck);
    k_bsum <<<nb, SCAN_T, 0, stream>>>(H, bsum, M);
    k_bscan<<<1, 512, 0, stream>>>(bsum, boff, nb);
    k_scan2<<<nb, SCAN_T, 0, stream>>>(H, boff, S, M, nE);
    k_scat <<<gb1, BLK, 0, stream>>>(tgt, src, S, bp, nE, gb1, nbuck);
    k_bcsr <<<nbuck, BLK, 0, stream>>>(S, bp, rowptr, col, dinv, n, gb1);
    k_embed<<<gN, BLK, 0, stream>>>(x, birth_t, gender_t, symp_t, W1, dinv, A16, n);
    k_gmid5<<<gNode, BLK, 0, stream>>>(rowptr, col, A16, dinv, W2, b1, Wl, z, n);
    k_gfin4<<<gN, BLK, 0, stream>>>(rowptr, col, z, dinv, b2, Wl, bl, out, n);
}